// Round 2
// baseline (1022.203 us; speedup 1.0000x reference)
//
#include <hip/hip_runtime.h>
#include <math.h>
#include <limits.h>

#define BSZ 16
#define NQ  900
#define NCL 92
#define NT  256
#define SUMT (BSZ*NT)   /* 4096 */
#define MM  NQ          /* JV columns (queries) */
#define NN  NT          /* JV rows (targets)    */
#define NSLOT 15        /* ceil(900/64) columns per lane */
#define QCHUNK 60       /* q's per cost block: 900 = 15*60 */

// ---------------------------------------------------------------------------
// Kernel A: softmax probs, one wave per (b,q) row, shuffle-only.
// ---------------------------------------------------------------------------
__global__ __launch_bounds__(256) void prob_kernel(
    const float* __restrict__ logits, float* __restrict__ P) {
#pragma clang fp contract(off)
  const int w = threadIdx.x >> 6, lane = threadIdx.x & 63;
  const int r = blockIdx.x * 4 + w;
  const size_t base = (size_t)r * NCL;
  const float x1 = logits[base + lane];
  const float x2 = (lane + 64 < NCL) ? logits[base + lane + 64] : -INFINITY;
  float m = fmaxf(x1, x2);
  #pragma unroll
  for (int k = 1; k < 64; k <<= 1) m = fmaxf(m, __shfl_xor(m, k));
  const float e1 = expf(x1 - m);
  const float e2 = (lane + 64 < NCL) ? expf(x2 - m) : 0.f;
  float ssum = e1 + e2;
  #pragma unroll
  for (int k = 1; k < 64; k <<= 1) ssum += __shfl_xor(ssum, k);
  P[base + lane] = e1 / ssum;
  if (lane + 64 < NCL) P[base + lane + 64] = e2 / ssum;
}

// ---------------------------------------------------------------------------
// Kernel B: cost matrix, coalesced stores; per-block LDS staging of the
// 60 query boxes + 60x92 prob rows so the q-loop is LDS+VALU only.
// ---------------------------------------------------------------------------
__global__ __launch_bounds__(256) void cost_kernel2(
    const float* __restrict__ P, const float* __restrict__ boxes,
    const int* __restrict__ labels, const float* __restrict__ tbox,
    float* __restrict__ C) {
#pragma clang fp contract(off)
  const int tid = threadIdx.x;
  const int jt = blockIdx.x * 256 + tid;
  const int b  = blockIdx.z;
  const int q0 = blockIdx.y * QCHUNK;

  __shared__ float sP[QCHUNK * NCL];   // 5520 floats
  __shared__ float sB[QCHUNK * 4];     // 240 floats

  const size_t pbase = (size_t)(b * NQ + q0) * NCL;
  for (int x = tid; x < QCHUNK * NCL; x += 256) sP[x] = P[pbase + x];
  const size_t bbase = (size_t)(b * NQ + q0) * 4;
  if (tid < QCHUNK * 4) sB[tid] = boxes[bbase + tid];

  const float4 tb = ((const float4*)tbox)[jt];
  const int lab = labels[jt];
  const float tx1 = tb.x - 0.5f*tb.z, ty1 = tb.y - 0.5f*tb.w;
  const float tx2 = tb.x + 0.5f*tb.z, ty2 = tb.y + 0.5f*tb.w;
  const float area2 = (tx2 - tx1) * (ty2 - ty1);
  __syncthreads();

  for (int qq = 0; qq < QCHUNK; ++qq) {
    const float cx = sB[qq*4+0], cy = sB[qq*4+1];
    const float w  = sB[qq*4+2], h  = sB[qq*4+3];
    const float cc = -sP[qq*NCL + lab];
    const float bx1 = cx - 0.5f*w, by1 = cy - 0.5f*h;
    const float bx2 = cx + 0.5f*w, by2 = cy + 0.5f*h;
    const float area1 = (bx2 - bx1) * (by2 - by1);
    const float d0 = fabsf(cx - tb.x), d1 = fabsf(cy - tb.y);
    const float d2 = fabsf(w - tb.z),  d3 = fabsf(h - tb.w);
    const float cb = ((d0 + d1) + d2) + d3;
    const float ltx = fmaxf(bx1, tx1), lty = fmaxf(by1, ty1);
    const float rbx = fminf(bx2, tx2), rby = fminf(by2, ty2);
    const float iw = fmaxf(rbx - ltx, 0.f), ih = fmaxf(rby - lty, 0.f);
    const float inter = iw * ih;
    const float uni = (area1 + area2) - inter;
    const float iou = inter / uni;
    const float ex1 = fminf(bx1, tx1), ey1 = fminf(by1, ty1);
    const float ex2 = fmaxf(bx2, tx2), ey2 = fmaxf(by2, ty2);
    const float ew = fmaxf(ex2 - ex1, 0.f), eh = fmaxf(ey2 - ey1, 0.f);
    const float ea = ew * eh;
    const float giou = iou - (ea - uni) / ea;
    C[(size_t)(b*NQ + q0 + qq) * SUMT + jt] = (5.0f*cb + 1.0f*cc) + 2.0f*(-giou);
  }
}

// ---------------------------------------------------------------------------
// Kernel C: LDS-tiled transpose of the diagonal slabs: costT[b][t][q].
// ---------------------------------------------------------------------------
__global__ __launch_bounds__(256) void transpose_kernel(
    const float* __restrict__ C, float* __restrict__ costT) {
  __shared__ float tile[64][65];
  const int b  = blockIdx.z;
  const int q0 = blockIdx.x * 64, t0 = blockIdx.y * 64;
  const int tx = threadIdx.x & 63, ty = threadIdx.x >> 6;
  #pragma unroll
  for (int i = 0; i < 16; ++i) {
    const int qq = ty + i*4;
    const int q = q0 + qq;
    if (q < NQ)
      tile[qq][tx] = C[((size_t)(b*NQ + q))*SUMT + b*NT + t0 + tx];
  }
  __syncthreads();
  #pragma unroll
  for (int i = 0; i < 16; ++i) {
    const int tt = ty + i*4;
    const int q = q0 + tx;
    if (q < NQ)
      costT[((size_t)(b*NT + t0 + tt))*MM + q] = tile[tx][tt];
  }
}

// ---------------------------------------------------------------------------
// Kernel C2: fully-parallel row minima over costT rows (one wave per row).
// Packs (ordered-float-key << 32) | col so u64-min == (min value, lowest col)
// exactly matching a sequential strict-< scan. Greedy "lowest row wins"
// claims via global atomicMin (claim[] pre-set to 0xFFFFFFFF).
// ---------------------------------------------------------------------------
__global__ __launch_bounds__(256) void rowmin_kernel(
    const float* __restrict__ costT, unsigned long long* __restrict__ upack,
    unsigned* __restrict__ claimg) {
  const int w = threadIdx.x >> 6, lane = threadIdx.x & 63;
  const int row = blockIdx.x * 4 + w;          // row = b*NN + t
  const float* rp = costT + (size_t)row * MM;
  unsigned long long best = ~0ull;
  #pragma unroll
  for (int s = 0; s < NSLOT; ++s) {
    const int j = s * 64 + lane;
    if (j < MM) {
      unsigned bts = __float_as_uint(rp[j]);
      bts = (bts & 0x80000000u) ? ~bts : (bts | 0x80000000u);
      const unsigned long long pk = ((unsigned long long)bts << 32) | (unsigned)j;
      if (pk < best) best = pk;
    }
  }
  #pragma unroll
  for (int m = 1; m < 64; m <<= 1) {
    const unsigned long long o = __shfl_xor(best, m);
    if (o < best) best = o;
  }
  if (lane == 0) {
    upack[row] = best;
    const int b = row >> 8;
    const int t = row & (NN - 1);
    const unsigned q = (unsigned)(best & 0xffffffffu);
    atomicMin(&claimg[b * MM + q], (unsigned)t);
  }
}

// ---------------------------------------------------------------------------
// Fallback cost kernel (used only if workspace is too small).
// ---------------------------------------------------------------------------
__global__ __launch_bounds__(256) void cost_kernel_fb(
    const float* __restrict__ logits, const float* __restrict__ boxes,
    const int* __restrict__ labels, const float* __restrict__ tbox,
    float* __restrict__ C, float* __restrict__ costT) {
#pragma clang fp contract(off)
  const int bq  = blockIdx.x;
  const int b   = bq / NQ;
  const int tid = threadIdx.x;
  __shared__ float lg[NCL];
  __shared__ float red[128];
  if (tid < NCL) lg[tid] = logits[(size_t)bq * NCL + tid];
  __syncthreads();
  if (tid < 128) red[tid] = (tid < NCL) ? lg[tid] : -INFINITY;
  __syncthreads();
  for (int s = 64; s > 0; s >>= 1) { if (tid < s) red[tid] = fmaxf(red[tid], red[tid+s]); __syncthreads(); }
  const float mx = red[0];
  __syncthreads();
  float e = 0.f;
  if (tid < NCL) e = expf(lg[tid] - mx);
  if (tid < 128) red[tid] = e;
  __syncthreads();
  for (int s = 64; s > 0; s >>= 1) { if (tid < s) red[tid] += red[tid+s]; __syncthreads(); }
  const float sm = red[0];
  __syncthreads();
  if (tid < NCL) lg[tid] = e / sm;
  __syncthreads();
  const float cx = boxes[(size_t)bq*4+0], cy = boxes[(size_t)bq*4+1];
  const float w  = boxes[(size_t)bq*4+2], h  = boxes[(size_t)bq*4+3];
  const float bx1 = cx - 0.5f*w, by1 = cy - 0.5f*h;
  const float bx2 = cx + 0.5f*w, by2 = cy + 0.5f*h;
  const float area1 = (bx2 - bx1) * (by2 - by1);
  const int q = bq - b * NQ;
  for (int jt = tid; jt < SUMT; jt += 256) {
    const float4 tb = ((const float4*)tbox)[jt];
    const int lab = labels[jt];
    const float cc = -lg[lab];
    const float d0 = fabsf(cx - tb.x), d1 = fabsf(cy - tb.y);
    const float d2 = fabsf(w - tb.z),  d3 = fabsf(h - tb.w);
    const float cb = ((d0 + d1) + d2) + d3;
    const float tx1 = tb.x - 0.5f*tb.z, ty1 = tb.y - 0.5f*tb.w;
    const float tx2 = tb.x + 0.5f*tb.z, ty2 = tb.y + 0.5f*tb.w;
    const float area2 = (tx2 - tx1) * (ty2 - ty1);
    const float ltx = fmaxf(bx1, tx1), lty = fmaxf(by1, ty1);
    const float rbx = fminf(bx2, tx2), rby = fminf(by2, ty2);
    const float iw = fmaxf(rbx - ltx, 0.f), ih = fmaxf(rby - lty, 0.f);
    const float inter = iw * ih;
    const float uni = (area1 + area2) - inter;
    const float iou = inter / uni;
    const float ex1 = fminf(bx1, tx1), ey1 = fminf(by1, ty1);
    const float ex2 = fmaxf(bx2, tx2), ey2 = fmaxf(by2, ty2);
    const float ew = fmaxf(ex2 - ex1, 0.f), eh = fmaxf(ey2 - ey1, 0.f);
    const float ea = ew * eh;
    const float giou = iou - (ea - uni) / ea;
    const float cval = (5.0f*cb + 1.0f*cc) + 2.0f*(-giou);
    C[(size_t)bq * SUMT + jt] = cval;
    if (costT && (jt >> 8) == b) costT[(size_t)jt * MM + q] = cval;
  }
}

// ---------------------------------------------------------------------------
// Kernel D: JV LSA.
// Phase A: duals u[i]=row-min + greedy claims (precomputed by rowmin_kernel
//   when upack!=null; else computed in-kernel by 256 threads).
// Phase A2 (wave 0): faithful LAPJV augmenting row reduction, 2 passes:
//   scan -> (mu1@j1, mu2@j2); u[i]=mu2; if mu1<mu2 strictly: v[j1]-=mu2-mu1,
//   steal j1, displaced row reprocessed IMMEDIATELY (v strictly decreased);
//   on exact tie: take j2 if j1 assigned (no v change), displaced row is
//   DEFERRED to the next pass (anti-ping-pong). Invariants (dual feasibility
//   + complementary slackness, exact f64) hold after every step, so Phase B
//   is exact no matter where ARR stops.
// Phase B (wave 0): Dijkstra for remaining unassigned rows, lazy deltas.
// ---------------------------------------------------------------------------
__global__ __launch_bounds__(256) void lsa_kernel(
    const float* __restrict__ C, const float* __restrict__ costT,
    const unsigned long long* __restrict__ upack,
    const unsigned* __restrict__ claimg,
    float* __restrict__ rows_out, float* __restrict__ cols_out) {
  const int b   = blockIdx.x;
  const int tid = threadIdx.x;

  __shared__ double u[NN + 1];
  __shared__ int    p[MM + 1];
  __shared__ int    wayl[MM + 1];
  __shared__ int    claim[MM + 1];
  __shared__ int    rowargmin[NN];
  __shared__ unsigned char rowass[NN];
  __shared__ int    listj[MM + 1];
  __shared__ double listD[MM + 1];
  __shared__ int    flist[NN];

  // ---- Phase A: row minima + greedy claims ----
  for (int j = tid; j <= MM; j += 256) { p[j] = 0; claim[j] = INT_MAX; }
  if (upack) {
    const unsigned long long pk = upack[b * NN + tid];
    const unsigned key = (unsigned)(pk >> 32);
    const unsigned bts = (key & 0x80000000u) ? (key & 0x7fffffffu) : ~key;
    const int am = (int)(pk & 0xffffffffu);
    u[tid + 1] = (double)__uint_as_float(bts);
    const bool got = (claimg[b * MM + am] == (unsigned)tid);
    rowass[tid] = got ? 1 : 0;
    if (got) p[am + 1] = tid + 1;
    if (tid == 0) u[0] = 0.0;
    __syncthreads();
  } else {
    const float* rowptr = C + ((size_t)(b * NQ)) * SUMT + b * NT + tid;
    float mn = INFINITY; int am = 0;
    #pragma unroll 4
    for (int q = 0; q < NQ; ++q) {
      const float cv = rowptr[(size_t)q * SUMT];
      if (cv < mn) { mn = cv; am = q; }
    }
    u[tid + 1] = (double)mn;     // exact: pure f32 min, no arithmetic
    rowargmin[tid] = am;
    if (tid == 0) u[0] = 0.0;
    __syncthreads();
    atomicMin(&claim[rowargmin[tid] + 1], tid + 1);
    __syncthreads();
    {
      const int am2 = rowargmin[tid];
      const bool got = (claim[am2 + 1] == tid + 1);
      rowass[tid] = got ? 1 : 0;
      if (got) p[am2 + 1] = tid + 1;
    }
    __syncthreads();
  }
  if (tid >= 64) return;                   // phases A2/B are wave 0 only

  const int lane = tid;
  const float* slab = costT ? costT + (size_t)b * NT * MM : nullptr;
  double v_r[NSLOT];
  #pragma unroll
  for (int s = 0; s < NSLOT; ++s) v_r[s] = 0.0;

  // ---- build free-row list (ascending row index) ----
  int fcnt = 0;
  #pragma unroll
  for (int c = 0; c < 4; ++c) {
    const bool fr = !rowass[c * 64 + lane];
    const unsigned long long mk = __ballot(fr);
    const int rk = __popcll(mk & ((1ull << lane) - 1ull));
    if (fr) flist[fcnt + rk] = c * 64 + lane + 1;
    fcnt += __popcll(mk);
  }

  // ---- Phase A2: LAPJV augmenting row reduction (wave 0, 2 passes) ----
  if (slab) {
    int steps = 0; const int CAP = 3000;
    int f = fcnt;
    for (int pass = 0; pass < 2 && steps < CAP; ++pass) {
      const int f0 = f; int h = 0; f = 0;
      while (h < f0 && steps < CAP) {
        const int i = flist[h++]; ++steps;
        const float* rowp = slab + (size_t)(i - 1) * MM;
        double b1 = INFINITY, b2 = INFINITY; int j1 = MM + 2, j2 = MM + 2;
        #pragma unroll
        for (int s = 0; s < NSLOT; ++s) {
          const int j = s * 64 + lane + 1;
          if (j <= MM) {
            const double cand = (double)rowp[j - 1] - v_r[s];
            if (cand < b1)      { b2 = b1; j2 = j1; b1 = cand; j1 = j; }
            else if (cand < b2) { b2 = cand; j2 = j; }
          }
        }
        #pragma unroll
        for (int m = 1; m < 64; m <<= 1) {
          const double ob1 = __shfl_xor(b1, m), ob2 = __shfl_xor(b2, m);
          const int    oj1 = __shfl_xor(j1, m), oj2 = __shfl_xor(j2, m);
          if (ob1 < b1 || (ob1 == b1 && oj1 < j1)) {
            if (b1 < ob2 || (b1 == ob2 && j1 < oj2)) { b2 = b1; j2 = j1; }
            else                                     { b2 = ob2; j2 = oj2; }
            b1 = ob1; j1 = oj1;
          } else {
            if (ob1 < b2 || (ob1 == b2 && oj1 < j2)) { b2 = ob1; j2 = oj1; }
          }
        }
        // uniform across lanes: (b1@j1, b2@j2), b1 <= b2
        const bool strict = (b1 < b2);
        int jt_ = j1;
        if (strict) {
          const double amt = b2 - b1;
          if (lane == ((j1 - 1) & 63)) v_r[(j1 - 1) >> 6] -= amt;
        } else if (p[j1] != 0) {
          jt_ = j2;              // tie: prefer untouched second column
        }
        const int k = p[jt_];    // read before overwrite (all lanes)
        if (lane == 0) {
          u[i] = b2;
          p[jt_] = i;
          rowass[i - 1] = 1;
          if (k) rowass[k - 1] = 0;
        }
        if (k) {
          if (strict) { if (lane == 0) flist[h - 1] = k; --h; }  // reprocess now
          else        { if (lane == 0) flist[f] = k; ++f; }      // defer to next pass
        }
      }
    }
  }

  // ---- Phase B: Dijkstra for any remaining unassigned rows (wave 0) ----
  for (int ii = 1; ii <= NN; ++ii) {
    if (rowass[ii - 1]) continue;

    double M_r[NSLOT];
    #pragma unroll
    for (int s = 0; s < NSLOT; ++s) M_r[s] = INFINITY;
    unsigned int used = (lane < 4) ? 0u : (1u << 14);  // kill slot-14 tail
    int    lcount = 0;
    int    j0 = 0;
    double Dsel = 0.0;          // D at j0's selection (0 for virtual col)
    double D = 0.0;

    while (true) {
      const int    i0 = (j0 == 0) ? ii : p[j0];
      const double us = u[i0] - Dsel;
      const float* rowp = slab ? slab + (size_t)(i0 - 1) * MM : nullptr;

      double best = INFINITY; int bestj = MM + 2;
      #pragma unroll
      for (int s = 0; s < NSLOT; ++s) {
        if (!(used & (1u << s))) {
          const int j = s * 64 + lane + 1;
          const float cf = rowp ? rowp[j - 1]
              : C[((size_t)(b*NQ + (j-1)))*SUMT + (b*NT + i0 - 1)];
          const double cand = ((double)cf - v_r[s]) - us;
          if (cand < M_r[s]) { M_r[s] = cand; wayl[j] = j0; }
          if (M_r[s] < best) { best = M_r[s]; bestj = j; }
        }
      }
      #pragma unroll
      for (int m = 1; m < 64; m <<= 1) {
        const double ov = __shfl_xor(best, m);
        const int    oj = __shfl_xor(bestj, m);
        if (ov < best || (ov == best && oj < bestj)) { best = ov; bestj = oj; }
      }
      const int j1 = bestj;
      D = best;                                  // accumulated delta = M[j1]
      if (lane == ((j1 - 1) & 63)) used |= 1u << ((j1 - 1) >> 6);
      if (p[j1] == 0) { j0 = j1; break; }        // free column: done
      if (lane == 0) { listj[lcount] = j1; listD[lcount] = D; }
      lcount++;
      j0 = j1; Dsel = D;
    }

    // batched dual updates (old p), then augmentation
    for (int e = 0; e < lcount; ++e) {
      const int    je = listj[e];
      const double amt = D - listD[e];
      if (lane == ((je - 1) & 63)) v_r[(je - 1) >> 6] -= amt;
      if (lane == 0) u[p[je]] += amt;
    }
    if (lane == 0) {
      u[ii] += D;                                // virtual column j0=0
      int jj = j0;
      while (jj) { const int jn = wayl[jj]; const int pn = (jn == 0) ? ii : p[jn]; p[jj] = pn; jj = jn; }
      rowass[ii - 1] = 1;
    }
  }

  // ---- emit (query, target) pairs in ascending query order ----
  int base = 0;
  #pragma unroll
  for (int s = 0; s < NSLOT; ++s) {
    const int j = s * 64 + lane + 1;
    const bool a = (j <= MM) && (p[j] > 0);
    const unsigned long long mask = __ballot(a);
    const int rank = __popcll(mask & ((1ull << lane) - 1ull));
    if (a) {
      rows_out[b*NT + base + rank] = (float)(j - 1);
      cols_out[b*NT + base + rank] = (float)(p[j] - 1);
    }
    base += __popcll(mask);
  }
}

extern "C" void kernel_launch(void* const* d_in, const int* in_sizes, int n_in,
                              void* d_out, int out_size, void* d_ws, size_t ws_size,
                              hipStream_t stream) {
  const float* logits = (const float*)d_in[0];
  const float* boxes  = (const float*)d_in[1];
  const int*   labels = (const int*)d_in[2];
  const float* tbox   = (const float*)d_in[3];

  float* C    = (float*)d_out;
  float* rows = C + (size_t)BSZ * NQ * SUMT;
  float* cols = rows + (size_t)BSZ * NT;

  const size_t needT = (size_t)SUMT * MM * sizeof(float);        // ~14.7 MB
  const size_t needP = (size_t)BSZ * NQ * NCL * sizeof(float);   // ~5.3 MB
  const size_t needU = (size_t)BSZ * NN * sizeof(unsigned long long);
  const size_t needC = (size_t)BSZ * MM * sizeof(unsigned);

  if (ws_size >= needP + needT + needU + needC) {
    float* P     = (float*)d_ws;
    float* costT = P + (size_t)BSZ * NQ * NCL;
    unsigned long long* upack = (unsigned long long*)(costT + (size_t)SUMT * MM);
    unsigned* claimg = (unsigned*)(upack + (size_t)BSZ * NN);
    hipMemsetAsync(claimg, 0xFF, needC, stream);
    hipLaunchKernelGGL(prob_kernel, dim3(BSZ*NQ/4), dim3(256), 0, stream, logits, P);
    hipLaunchKernelGGL(cost_kernel2, dim3(SUMT/256, NQ/QCHUNK, BSZ), dim3(256), 0, stream,
                       P, boxes, labels, tbox, C);
    hipLaunchKernelGGL(transpose_kernel, dim3(15, 4, BSZ), dim3(256), 0, stream, C, costT);
    hipLaunchKernelGGL(rowmin_kernel, dim3(BSZ*NN/4), dim3(256), 0, stream, costT, upack, claimg);
    hipLaunchKernelGGL(lsa_kernel, dim3(BSZ), dim3(256), 0, stream,
                       C, costT, upack, claimg, rows, cols);
  } else if (ws_size >= needP + needT) {
    float* P     = (float*)d_ws;
    float* costT = P + (size_t)BSZ * NQ * NCL;
    hipLaunchKernelGGL(prob_kernel, dim3(BSZ*NQ/4), dim3(256), 0, stream, logits, P);
    hipLaunchKernelGGL(cost_kernel2, dim3(SUMT/256, NQ/QCHUNK, BSZ), dim3(256), 0, stream,
                       P, boxes, labels, tbox, C);
    hipLaunchKernelGGL(transpose_kernel, dim3(15, 4, BSZ), dim3(256), 0, stream, C, costT);
    hipLaunchKernelGGL(lsa_kernel, dim3(BSZ), dim3(256), 0, stream,
                       C, costT, (const unsigned long long*)nullptr,
                       (const unsigned*)nullptr, rows, cols);
  } else if (ws_size >= needT) {
    float* costT = (float*)d_ws;
    hipLaunchKernelGGL(cost_kernel_fb, dim3(BSZ*NQ), dim3(256), 0, stream,
                       logits, boxes, labels, tbox, C, costT);
    hipLaunchKernelGGL(lsa_kernel, dim3(BSZ), dim3(256), 0, stream,
                       C, costT, (const unsigned long long*)nullptr,
                       (const unsigned*)nullptr, rows, cols);
  } else {
    hipLaunchKernelGGL(cost_kernel_fb, dim3(BSZ*NQ), dim3(256), 0, stream,
                       logits, boxes, labels, tbox, C, (float*)nullptr);
    hipLaunchKernelGGL(lsa_kernel, dim3(BSZ), dim3(256), 0, stream,
                       C, (float*)nullptr, (const unsigned long long*)nullptr,
                       (const unsigned*)nullptr, rows, cols);
  }
}

// Round 3
// 1011.544 us; speedup vs baseline: 1.0105x; 1.0105x over previous
//
#include <hip/hip_runtime.h>
#include <math.h>
#include <limits.h>

#define BSZ 16
#define NQ  900
#define NCL 92
#define NT  256
#define SUMT (BSZ*NT)   /* 4096 */
#define MM  NQ          /* JV columns (queries) */
#define NN  NT          /* JV rows (targets)    */
#define NSLOT 15        /* ceil(900/64) columns per lane */
#define QCHUNK 60       /* q's per cost block: 900 = 15*60 */

// ---------------------------------------------------------------------------
// Kernel A: softmax probs, one wave per (b,q) row, shuffle-only.
// ---------------------------------------------------------------------------
__global__ __launch_bounds__(256) void prob_kernel(
    const float* __restrict__ logits, float* __restrict__ P) {
#pragma clang fp contract(off)
  const int w = threadIdx.x >> 6, lane = threadIdx.x & 63;
  const int r = blockIdx.x * 4 + w;
  const size_t base = (size_t)r * NCL;
  const float x1 = logits[base + lane];
  const float x2 = (lane + 64 < NCL) ? logits[base + lane + 64] : -INFINITY;
  float m = fmaxf(x1, x2);
  #pragma unroll
  for (int k = 1; k < 64; k <<= 1) m = fmaxf(m, __shfl_xor(m, k));
  const float e1 = expf(x1 - m);
  const float e2 = (lane + 64 < NCL) ? expf(x2 - m) : 0.f;
  float ssum = e1 + e2;
  #pragma unroll
  for (int k = 1; k < 64; k <<= 1) ssum += __shfl_xor(ssum, k);
  P[base + lane] = e1 / ssum;
  if (lane + 64 < NCL) P[base + lane + 64] = e2 / ssum;
}

// ---------------------------------------------------------------------------
// Kernel B: cost matrix, coalesced stores; per-block LDS staging of the
// 60 query boxes + 60x92 prob rows so the q-loop is LDS+VALU only.
// ---------------------------------------------------------------------------
__global__ __launch_bounds__(256) void cost_kernel2(
    const float* __restrict__ P, const float* __restrict__ boxes,
    const int* __restrict__ labels, const float* __restrict__ tbox,
    float* __restrict__ C) {
#pragma clang fp contract(off)
  const int tid = threadIdx.x;
  const int jt = blockIdx.x * 256 + tid;
  const int b  = blockIdx.z;
  const int q0 = blockIdx.y * QCHUNK;

  __shared__ float sP[QCHUNK * NCL];   // 5520 floats
  __shared__ float sB[QCHUNK * 4];     // 240 floats

  const size_t pbase = (size_t)(b * NQ + q0) * NCL;
  for (int x = tid; x < QCHUNK * NCL; x += 256) sP[x] = P[pbase + x];
  const size_t bbase = (size_t)(b * NQ + q0) * 4;
  if (tid < QCHUNK * 4) sB[tid] = boxes[bbase + tid];

  const float4 tb = ((const float4*)tbox)[jt];
  const int lab = labels[jt];
  const float tx1 = tb.x - 0.5f*tb.z, ty1 = tb.y - 0.5f*tb.w;
  const float tx2 = tb.x + 0.5f*tb.z, ty2 = tb.y + 0.5f*tb.w;
  const float area2 = (tx2 - tx1) * (ty2 - ty1);
  __syncthreads();

  for (int qq = 0; qq < QCHUNK; ++qq) {
    const float cx = sB[qq*4+0], cy = sB[qq*4+1];
    const float w  = sB[qq*4+2], h  = sB[qq*4+3];
    const float cc = -sP[qq*NCL + lab];
    const float bx1 = cx - 0.5f*w, by1 = cy - 0.5f*h;
    const float bx2 = cx + 0.5f*w, by2 = cy + 0.5f*h;
    const float area1 = (bx2 - bx1) * (by2 - by1);
    const float d0 = fabsf(cx - tb.x), d1 = fabsf(cy - tb.y);
    const float d2 = fabsf(w - tb.z),  d3 = fabsf(h - tb.w);
    const float cb = ((d0 + d1) + d2) + d3;
    const float ltx = fmaxf(bx1, tx1), lty = fmaxf(by1, ty1);
    const float rbx = fminf(bx2, tx2), rby = fminf(by2, ty2);
    const float iw = fmaxf(rbx - ltx, 0.f), ih = fmaxf(rby - lty, 0.f);
    const float inter = iw * ih;
    const float uni = (area1 + area2) - inter;
    const float iou = inter / uni;
    const float ex1 = fminf(bx1, tx1), ey1 = fminf(by1, ty1);
    const float ex2 = fmaxf(bx2, tx2), ey2 = fmaxf(by2, ty2);
    const float ew = fmaxf(ex2 - ex1, 0.f), eh = fmaxf(ey2 - ey1, 0.f);
    const float ea = ew * eh;
    const float giou = iou - (ea - uni) / ea;
    C[(size_t)(b*NQ + q0 + qq) * SUMT + jt] = (5.0f*cb + 1.0f*cc) + 2.0f*(-giou);
  }
}

// ---------------------------------------------------------------------------
// Kernel C: LDS-tiled transpose of the diagonal slabs: costT[b][t][q].
// ---------------------------------------------------------------------------
__global__ __launch_bounds__(256) void transpose_kernel(
    const float* __restrict__ C, float* __restrict__ costT) {
  __shared__ float tile[64][65];
  const int b  = blockIdx.z;
  const int q0 = blockIdx.x * 64, t0 = blockIdx.y * 64;
  const int tx = threadIdx.x & 63, ty = threadIdx.x >> 6;
  #pragma unroll
  for (int i = 0; i < 16; ++i) {
    const int qq = ty + i*4;
    const int q = q0 + qq;
    if (q < NQ)
      tile[qq][tx] = C[((size_t)(b*NQ + q))*SUMT + b*NT + t0 + tx];
  }
  __syncthreads();
  #pragma unroll
  for (int i = 0; i < 16; ++i) {
    const int tt = ty + i*4;
    const int q = q0 + tx;
    if (q < NQ)
      costT[((size_t)(b*NT + t0 + tt))*MM + q] = tile[tx][tt];
  }
}

// ---------------------------------------------------------------------------
// Kernel C2: fully-parallel row minima over costT rows (one wave per row).
// Packs (ordered-float-key << 32) | col so u64-min == (min value, lowest col)
// exactly matching a sequential strict-< scan. Greedy "lowest row wins"
// claims via global atomicMin (claim[] pre-set to 0xFFFFFFFF).
// ---------------------------------------------------------------------------
__global__ __launch_bounds__(256) void rowmin_kernel(
    const float* __restrict__ costT, unsigned long long* __restrict__ upack,
    unsigned* __restrict__ claimg) {
  const int w = threadIdx.x >> 6, lane = threadIdx.x & 63;
  const int row = blockIdx.x * 4 + w;          // row = b*NN + t
  const float* rp = costT + (size_t)row * MM;
  unsigned long long best = ~0ull;
  #pragma unroll
  for (int s = 0; s < NSLOT; ++s) {
    const int j = s * 64 + lane;
    if (j < MM) {
      unsigned bts = __float_as_uint(rp[j]);
      bts = (bts & 0x80000000u) ? ~bts : (bts | 0x80000000u);
      const unsigned long long pk = ((unsigned long long)bts << 32) | (unsigned)j;
      if (pk < best) best = pk;
    }
  }
  #pragma unroll
  for (int m = 1; m < 64; m <<= 1) {
    const unsigned long long o = __shfl_xor(best, m);
    if (o < best) best = o;
  }
  if (lane == 0) {
    upack[row] = best;
    const int b = row >> 8;
    const int t = row & (NN - 1);
    const unsigned q = (unsigned)(best & 0xffffffffu);
    atomicMin(&claimg[b * MM + q], (unsigned)t);
  }
}

// ---------------------------------------------------------------------------
// Fallback cost kernel (used only if workspace is too small).
// ---------------------------------------------------------------------------
__global__ __launch_bounds__(256) void cost_kernel_fb(
    const float* __restrict__ logits, const float* __restrict__ boxes,
    const int* __restrict__ labels, const float* __restrict__ tbox,
    float* __restrict__ C, float* __restrict__ costT) {
#pragma clang fp contract(off)
  const int bq  = blockIdx.x;
  const int b   = bq / NQ;
  const int tid = threadIdx.x;
  __shared__ float lg[NCL];
  __shared__ float red[128];
  if (tid < NCL) lg[tid] = logits[(size_t)bq * NCL + tid];
  __syncthreads();
  if (tid < 128) red[tid] = (tid < NCL) ? lg[tid] : -INFINITY;
  __syncthreads();
  for (int s = 64; s > 0; s >>= 1) { if (tid < s) red[tid] = fmaxf(red[tid], red[tid+s]); __syncthreads(); }
  const float mx = red[0];
  __syncthreads();
  float e = 0.f;
  if (tid < NCL) e = expf(lg[tid] - mx);
  if (tid < 128) red[tid] = e;
  __syncthreads();
  for (int s = 64; s > 0; s >>= 1) { if (tid < s) red[tid] += red[tid+s]; __syncthreads(); }
  const float sm = red[0];
  __syncthreads();
  if (tid < NCL) lg[tid] = e / sm;
  __syncthreads();
  const float cx = boxes[(size_t)bq*4+0], cy = boxes[(size_t)bq*4+1];
  const float w  = boxes[(size_t)bq*4+2], h  = boxes[(size_t)bq*4+3];
  const float bx1 = cx - 0.5f*w, by1 = cy - 0.5f*h;
  const float bx2 = cx + 0.5f*w, by2 = cy + 0.5f*h;
  const float area1 = (bx2 - bx1) * (by2 - by1);
  const int q = bq - b * NQ;
  for (int jt = tid; jt < SUMT; jt += 256) {
    const float4 tb = ((const float4*)tbox)[jt];
    const int lab = labels[jt];
    const float cc = -lg[lab];
    const float d0 = fabsf(cx - tb.x), d1 = fabsf(cy - tb.y);
    const float d2 = fabsf(w - tb.z),  d3 = fabsf(h - tb.w);
    const float cb = ((d0 + d1) + d2) + d3;
    const float tx1 = tb.x - 0.5f*tb.z, ty1 = tb.y - 0.5f*tb.w;
    const float tx2 = tb.x + 0.5f*tb.z, ty2 = tb.y + 0.5f*tb.w;
    const float area2 = (tx2 - tx1) * (ty2 - ty1);
    const float ltx = fmaxf(bx1, tx1), lty = fmaxf(by1, ty1);
    const float rbx = fminf(bx2, tx2), rby = fminf(by2, ty2);
    const float iw = fmaxf(rbx - ltx, 0.f), ih = fmaxf(rby - lty, 0.f);
    const float inter = iw * ih;
    const float uni = (area1 + area2) - inter;
    const float iou = inter / uni;
    const float ex1 = fminf(bx1, tx1), ey1 = fminf(by1, ty1);
    const float ex2 = fmaxf(bx2, tx2), ey2 = fmaxf(by2, ty2);
    const float ew = fmaxf(ex2 - ex1, 0.f), eh = fmaxf(ey2 - ey1, 0.f);
    const float ea = ew * eh;
    const float giou = iou - (ea - uni) / ea;
    const float cval = (5.0f*cb + 1.0f*cc) + 2.0f*(-giou);
    C[(size_t)bq * SUMT + jt] = cval;
    if (costT && (jt >> 8) == b) costT[(size_t)jt * MM + q] = cval;
  }
}

// ---------------------------------------------------------------------------
// Kernel D: JV LSA.
// Phase A: duals u[i]=row-min + greedy claims (precomputed by rowmin_kernel
//   when upack!=null; else computed in-kernel by 256 threads).
// Phase A2 (wave 0): LAPJV augmenting row reduction, 2 passes, with a
//   CHAIN CAP (4) and a tight GLOBAL CAP (400 scans). Steal-chains longer
//   than the cap are epsilon-progress fights -> break and defer. Deferred /
//   unprocessed rows stay unassigned. Invariants (f64 dual feasibility +
//   complementary slackness) hold after EVERY step, so Phase B is exact
//   regardless of where ARR stops.
// Phase B (wave 0): Dijkstra for remaining unassigned rows, lazy deltas.
// ---------------------------------------------------------------------------
__global__ __launch_bounds__(256) void lsa_kernel(
    const float* __restrict__ C, const float* __restrict__ costT,
    const unsigned long long* __restrict__ upack,
    const unsigned* __restrict__ claimg,
    float* __restrict__ rows_out, float* __restrict__ cols_out) {
  const int b   = blockIdx.x;
  const int tid = threadIdx.x;

  __shared__ double u[NN + 1];
  __shared__ int    p[MM + 1];
  __shared__ int    wayl[MM + 1];
  __shared__ int    claim[MM + 1];
  __shared__ int    rowargmin[NN];
  __shared__ unsigned char rowass[NN];
  __shared__ int    listj[MM + 1];
  __shared__ double listD[MM + 1];
  __shared__ int    fl[2][NN];

  // ---- Phase A: row minima + greedy claims ----
  for (int j = tid; j <= MM; j += 256) { p[j] = 0; claim[j] = INT_MAX; }
  if (upack) {
    const unsigned long long pk = upack[b * NN + tid];
    const unsigned key = (unsigned)(pk >> 32);
    const unsigned bts = (key & 0x80000000u) ? (key & 0x7fffffffu) : ~key;
    const int am = (int)(pk & 0xffffffffu);
    u[tid + 1] = (double)__uint_as_float(bts);
    const bool got = (claimg[b * MM + am] == (unsigned)tid);
    rowass[tid] = got ? 1 : 0;
    if (got) p[am + 1] = tid + 1;
    if (tid == 0) u[0] = 0.0;
    __syncthreads();
  } else {
    const float* rowptr = C + ((size_t)(b * NQ)) * SUMT + b * NT + tid;
    float mn = INFINITY; int am = 0;
    #pragma unroll 4
    for (int q = 0; q < NQ; ++q) {
      const float cv = rowptr[(size_t)q * SUMT];
      if (cv < mn) { mn = cv; am = q; }
    }
    u[tid + 1] = (double)mn;     // exact: pure f32 min, no arithmetic
    rowargmin[tid] = am;
    if (tid == 0) u[0] = 0.0;
    __syncthreads();
    atomicMin(&claim[rowargmin[tid] + 1], tid + 1);
    __syncthreads();
    {
      const int am2 = rowargmin[tid];
      const bool got = (claim[am2 + 1] == tid + 1);
      rowass[tid] = got ? 1 : 0;
      if (got) p[am2 + 1] = tid + 1;
    }
    __syncthreads();
  }
  if (tid >= 64) return;                   // phases A2/B are wave 0 only

  const int lane = tid;
  const float* slab = costT ? costT + (size_t)b * NT * MM : nullptr;
  double v_r[NSLOT];
  #pragma unroll
  for (int s = 0; s < NSLOT; ++s) v_r[s] = 0.0;

  // ---- build free-row list (ascending row index) into fl[0] ----
  int fcnt = 0;
  #pragma unroll
  for (int c = 0; c < 4; ++c) {
    const bool fr = !rowass[c * 64 + lane];
    const unsigned long long mk = __ballot(fr);
    const int rk = __popcll(mk & ((1ull << lane) - 1ull));
    if (fr) fl[0][fcnt + rk] = c * 64 + lane + 1;
    fcnt += __popcll(mk);
  }

  // ---- Phase A2: LAPJV ARR with chain cap (wave 0, 2 passes) ----
  if (slab) {
    int steps = 0;
    const int CAP = 400, CHAINMAX = 4;
    int cur = 0, cnt_cur = fcnt, cnt_nxt = 0;
    for (int pass = 0; pass < 2; ++pass) {
      int h = 0;
      while (h < cnt_cur && steps < CAP) {
        int i = fl[cur][h++];
        int chain = 0;
        while (true) {
          ++steps; ++chain;
          const float* rowp = slab + (size_t)(i - 1) * MM;
          double b1 = INFINITY, b2 = INFINITY; int j1 = MM + 2, j2 = MM + 2;
          #pragma unroll
          for (int s = 0; s < NSLOT; ++s) {
            const int j = s * 64 + lane + 1;
            if (j <= MM) {
              const double cand = (double)rowp[j - 1] - v_r[s];
              if (cand < b1)      { b2 = b1; j2 = j1; b1 = cand; j1 = j; }
              else if (cand < b2) { b2 = cand; j2 = j; }
            }
          }
          #pragma unroll
          for (int m = 1; m < 64; m <<= 1) {
            const double ob1 = __shfl_xor(b1, m), ob2 = __shfl_xor(b2, m);
            const int    oj1 = __shfl_xor(j1, m), oj2 = __shfl_xor(j2, m);
            if (ob1 < b1 || (ob1 == b1 && oj1 < j1)) {
              if (b1 < ob2 || (b1 == ob2 && j1 < oj2)) { b2 = b1; j2 = j1; }
              else                                     { b2 = ob2; j2 = oj2; }
              b1 = ob1; j1 = oj1;
            } else {
              if (ob1 < b2 || (ob1 == b2 && oj1 < j2)) { b2 = ob1; j2 = oj1; }
            }
          }
          // uniform across lanes: (b1@j1, b2@j2), b1 <= b2
          const bool strict = (b1 < b2);
          int jt_ = j1;
          if (!strict && p[j1] != 0) jt_ = j2;     // tie: prefer free 2nd col
          if (strict) {
            const double amt = b2 - b1;
            if (lane == ((j1 - 1) & 63)) v_r[(j1 - 1) >> 6] -= amt;
          }
          const int k = p[jt_];                    // read before overwrite
          if (lane == 0) {
            u[i] = b2;
            p[jt_] = i;
            rowass[i - 1] = 1;
            if (k) rowass[k - 1] = 0;
          }
          if (k == 0) break;                       // chain hit a free column
          if (!strict || chain >= CHAINMAX || steps >= CAP) {
            if (lane == 0) fl[cur ^ 1][cnt_nxt] = k;
            ++cnt_nxt;                             // defer displaced row
            break;
          }
          i = k;                                   // continue chain
        }
      }
      cur ^= 1; cnt_cur = cnt_nxt; cnt_nxt = 0;
    }
  }

  // ---- Phase B: Dijkstra for any remaining unassigned rows (wave 0) ----
  for (int ii = 1; ii <= NN; ++ii) {
    if (rowass[ii - 1]) continue;

    double M_r[NSLOT];
    #pragma unroll
    for (int s = 0; s < NSLOT; ++s) M_r[s] = INFINITY;
    unsigned int used = (lane < 4) ? 0u : (1u << 14);  // kill slot-14 tail
    int    lcount = 0;
    int    j0 = 0;
    double Dsel = 0.0;          // D at j0's selection (0 for virtual col)
    double D = 0.0;

    while (true) {
      const int    i0 = (j0 == 0) ? ii : p[j0];
      const double us = u[i0] - Dsel;
      const float* rowp = slab ? slab + (size_t)(i0 - 1) * MM : nullptr;

      double best = INFINITY; int bestj = MM + 2;
      #pragma unroll
      for (int s = 0; s < NSLOT; ++s) {
        if (!(used & (1u << s))) {
          const int j = s * 64 + lane + 1;
          const float cf = rowp ? rowp[j - 1]
              : C[((size_t)(b*NQ + (j-1)))*SUMT + (b*NT + i0 - 1)];
          const double cand = ((double)cf - v_r[s]) - us;
          if (cand < M_r[s]) { M_r[s] = cand; wayl[j] = j0; }
          if (M_r[s] < best) { best = M_r[s]; bestj = j; }
        }
      }
      #pragma unroll
      for (int m = 1; m < 64; m <<= 1) {
        const double ov = __shfl_xor(best, m);
        const int    oj = __shfl_xor(bestj, m);
        if (ov < best || (ov == best && oj < bestj)) { best = ov; bestj = oj; }
      }
      const int j1 = bestj;
      D = best;                                  // accumulated delta = M[j1]
      if (lane == ((j1 - 1) & 63)) used |= 1u << ((j1 - 1) >> 6);
      if (p[j1] == 0) { j0 = j1; break; }        // free column: done
      if (lane == 0) { listj[lcount] = j1; listD[lcount] = D; }
      lcount++;
      j0 = j1; Dsel = D;
    }

    // batched dual updates (old p), then augmentation
    for (int e = 0; e < lcount; ++e) {
      const int    je = listj[e];
      const double amt = D - listD[e];
      if (lane == ((je - 1) & 63)) v_r[(je - 1) >> 6] -= amt;
      if (lane == 0) u[p[je]] += amt;
    }
    if (lane == 0) {
      u[ii] += D;                                // virtual column j0=0
      int jj = j0;
      while (jj) { const int jn = wayl[jj]; const int pn = (jn == 0) ? ii : p[jn]; p[jj] = pn; jj = jn; }
      rowass[ii - 1] = 1;
    }
  }

  // ---- emit (query, target) pairs in ascending query order ----
  int base = 0;
  #pragma unroll
  for (int s = 0; s < NSLOT; ++s) {
    const int j = s * 64 + lane + 1;
    const bool a = (j <= MM) && (p[j] > 0);
    const unsigned long long mask = __ballot(a);
    const int rank = __popcll(mask & ((1ull << lane) - 1ull));
    if (a) {
      rows_out[b*NT + base + rank] = (float)(j - 1);
      cols_out[b*NT + base + rank] = (float)(p[j] - 1);
    }
    base += __popcll(mask);
  }
}

extern "C" void kernel_launch(void* const* d_in, const int* in_sizes, int n_in,
                              void* d_out, int out_size, void* d_ws, size_t ws_size,
                              hipStream_t stream) {
  const float* logits = (const float*)d_in[0];
  const float* boxes  = (const float*)d_in[1];
  const int*   labels = (const int*)d_in[2];
  const float* tbox   = (const float*)d_in[3];

  float* C    = (float*)d_out;
  float* rows = C + (size_t)BSZ * NQ * SUMT;
  float* cols = rows + (size_t)BSZ * NT;

  const size_t needT = (size_t)SUMT * MM * sizeof(float);        // ~14.7 MB
  const size_t needP = (size_t)BSZ * NQ * NCL * sizeof(float);   // ~5.3 MB
  const size_t needU = (size_t)BSZ * NN * sizeof(unsigned long long);
  const size_t needC = (size_t)BSZ * MM * sizeof(unsigned);

  if (ws_size >= needP + needT + needU + needC) {
    float* P     = (float*)d_ws;
    float* costT = P + (size_t)BSZ * NQ * NCL;
    unsigned long long* upack = (unsigned long long*)(costT + (size_t)SUMT * MM);
    unsigned* claimg = (unsigned*)(upack + (size_t)BSZ * NN);
    hipMemsetAsync(claimg, 0xFF, needC, stream);
    hipLaunchKernelGGL(prob_kernel, dim3(BSZ*NQ/4), dim3(256), 0, stream, logits, P);
    hipLaunchKernelGGL(cost_kernel2, dim3(SUMT/256, NQ/QCHUNK, BSZ), dim3(256), 0, stream,
                       P, boxes, labels, tbox, C);
    hipLaunchKernelGGL(transpose_kernel, dim3(15, 4, BSZ), dim3(256), 0, stream, C, costT);
    hipLaunchKernelGGL(rowmin_kernel, dim3(BSZ*NN/4), dim3(256), 0, stream, costT, upack, claimg);
    hipLaunchKernelGGL(lsa_kernel, dim3(BSZ), dim3(256), 0, stream,
                       C, costT, upack, claimg, rows, cols);
  } else if (ws_size >= needP + needT) {
    float* P     = (float*)d_ws;
    float* costT = P + (size_t)BSZ * NQ * NCL;
    hipLaunchKernelGGL(prob_kernel, dim3(BSZ*NQ/4), dim3(256), 0, stream, logits, P);
    hipLaunchKernelGGL(cost_kernel2, dim3(SUMT/256, NQ/QCHUNK, BSZ), dim3(256), 0, stream,
                       P, boxes, labels, tbox, C);
    hipLaunchKernelGGL(transpose_kernel, dim3(15, 4, BSZ), dim3(256), 0, stream, C, costT);
    hipLaunchKernelGGL(lsa_kernel, dim3(BSZ), dim3(256), 0, stream,
                       C, costT, (const unsigned long long*)nullptr,
                       (const unsigned*)nullptr, rows, cols);
  } else if (ws_size >= needT) {
    float* costT = (float*)d_ws;
    hipLaunchKernelGGL(cost_kernel_fb, dim3(BSZ*NQ), dim3(256), 0, stream,
                       logits, boxes, labels, tbox, C, costT);
    hipLaunchKernelGGL(lsa_kernel, dim3(BSZ), dim3(256), 0, stream,
                       C, costT, (const unsigned long long*)nullptr,
                       (const unsigned*)nullptr, rows, cols);
  } else {
    hipLaunchKernelGGL(cost_kernel_fb, dim3(BSZ*NQ), dim3(256), 0, stream,
                       logits, boxes, labels, tbox, C, (float*)nullptr);
    hipLaunchKernelGGL(lsa_kernel, dim3(BSZ), dim3(256), 0, stream,
                       C, (float*)nullptr, (const unsigned long long*)nullptr,
                       (const unsigned*)nullptr, rows, cols);
  }
}

// Round 6
// 603.076 us; speedup vs baseline: 1.6950x; 1.6773x over previous
//
#include <hip/hip_runtime.h>
#include <math.h>
#include <limits.h>

#define BSZ 16
#define NQ  900
#define NCL 92
#define NT  256
#define SUMT (BSZ*NT)   /* 4096 */
#define MM  NQ          /* JV columns (queries) */
#define NN  NT          /* JV rows (targets)    */
#define NSLOT 15        /* ceil(900/64) columns per lane */
#define QCHUNK 60       /* q's per cost block: 900 = 15*60 */

// ---------------------------------------------------------------------------
// Kernel A: softmax probs, one wave per (b,q) row, shuffle-only.
// ---------------------------------------------------------------------------
__global__ __launch_bounds__(256) void prob_kernel(
    const float* __restrict__ logits, float* __restrict__ P) {
#pragma clang fp contract(off)
  const int w = threadIdx.x >> 6, lane = threadIdx.x & 63;
  const int r = blockIdx.x * 4 + w;
  const size_t base = (size_t)r * NCL;
  const float x1 = logits[base + lane];
  const float x2 = (lane + 64 < NCL) ? logits[base + lane + 64] : -INFINITY;
  float m = fmaxf(x1, x2);
  #pragma unroll
  for (int k = 1; k < 64; k <<= 1) m = fmaxf(m, __shfl_xor(m, k));
  const float e1 = expf(x1 - m);
  const float e2 = (lane + 64 < NCL) ? expf(x2 - m) : 0.f;
  float ssum = e1 + e2;
  #pragma unroll
  for (int k = 1; k < 64; k <<= 1) ssum += __shfl_xor(ssum, k);
  P[base + lane] = e1 / ssum;
  if (lane + 64 < NCL) P[base + lane + 64] = e2 / ssum;
}

// ---------------------------------------------------------------------------
// Kernel B: cost matrix, coalesced stores; per-block LDS staging of the
// 60 query boxes + 60x92 prob rows so the q-loop is LDS+VALU only.
// ---------------------------------------------------------------------------
__global__ __launch_bounds__(256) void cost_kernel2(
    const float* __restrict__ P, const float* __restrict__ boxes,
    const int* __restrict__ labels, const float* __restrict__ tbox,
    float* __restrict__ C) {
#pragma clang fp contract(off)
  const int tid = threadIdx.x;
  const int jt = blockIdx.x * 256 + tid;
  const int b  = blockIdx.z;
  const int q0 = blockIdx.y * QCHUNK;

  __shared__ float sP[QCHUNK * NCL];   // 5520 floats
  __shared__ float sB[QCHUNK * 4];     // 240 floats

  const size_t pbase = (size_t)(b * NQ + q0) * NCL;
  for (int x = tid; x < QCHUNK * NCL; x += 256) sP[x] = P[pbase + x];
  const size_t bbase = (size_t)(b * NQ + q0) * 4;
  if (tid < QCHUNK * 4) sB[tid] = boxes[bbase + tid];

  const float4 tb = ((const float4*)tbox)[jt];
  const int lab = labels[jt];
  const float tx1 = tb.x - 0.5f*tb.z, ty1 = tb.y - 0.5f*tb.w;
  const float tx2 = tb.x + 0.5f*tb.z, ty2 = tb.y + 0.5f*tb.w;
  const float area2 = (tx2 - tx1) * (ty2 - ty1);
  __syncthreads();

  for (int qq = 0; qq < QCHUNK; ++qq) {
    const float cx = sB[qq*4+0], cy = sB[qq*4+1];
    const float w  = sB[qq*4+2], h  = sB[qq*4+3];
    const float cc = -sP[qq*NCL + lab];
    const float bx1 = cx - 0.5f*w, by1 = cy - 0.5f*h;
    const float bx2 = cx + 0.5f*w, by2 = cy + 0.5f*h;
    const float area1 = (bx2 - bx1) * (by2 - by1);
    const float d0 = fabsf(cx - tb.x), d1 = fabsf(cy - tb.y);
    const float d2 = fabsf(w - tb.z),  d3 = fabsf(h - tb.w);
    const float cb = ((d0 + d1) + d2) + d3;
    const float ltx = fmaxf(bx1, tx1), lty = fmaxf(by1, ty1);
    const float rbx = fminf(bx2, tx2), rby = fminf(by2, ty2);
    const float iw = fmaxf(rbx - ltx, 0.f), ih = fmaxf(rby - lty, 0.f);
    const float inter = iw * ih;
    const float uni = (area1 + area2) - inter;
    const float iou = inter / uni;
    const float ex1 = fminf(bx1, tx1), ey1 = fminf(by1, ty1);
    const float ex2 = fmaxf(bx2, tx2), ey2 = fmaxf(by2, ty2);
    const float ew = fmaxf(ex2 - ex1, 0.f), eh = fmaxf(ey2 - ey1, 0.f);
    const float ea = ew * eh;
    const float giou = iou - (ea - uni) / ea;
    C[(size_t)(b*NQ + q0 + qq) * SUMT + jt] = (5.0f*cb + 1.0f*cc) + 2.0f*(-giou);
  }
}

// ---------------------------------------------------------------------------
// Kernel C: LDS-tiled transpose of the diagonal slabs: costT[b][t][q].
// ---------------------------------------------------------------------------
__global__ __launch_bounds__(256) void transpose_kernel(
    const float* __restrict__ C, float* __restrict__ costT) {
  __shared__ float tile[64][65];
  const int b  = blockIdx.z;
  const int q0 = blockIdx.x * 64, t0 = blockIdx.y * 64;
  const int tx = threadIdx.x & 63, ty = threadIdx.x >> 6;
  #pragma unroll
  for (int i = 0; i < 16; ++i) {
    const int qq = ty + i*4;
    const int q = q0 + qq;
    if (q < NQ)
      tile[qq][tx] = C[((size_t)(b*NQ + q))*SUMT + b*NT + t0 + tx];
  }
  __syncthreads();
  #pragma unroll
  for (int i = 0; i < 16; ++i) {
    const int tt = ty + i*4;
    const int q = q0 + tx;
    if (q < NQ)
      costT[((size_t)(b*NT + t0 + tt))*MM + q] = tile[tx][tt];
  }
}

// ---------------------------------------------------------------------------
// Kernel C2: fully-parallel row minima over costT rows (one wave per row).
// Packs (ordered-float-key << 32) | col so u64-min == (min value, lowest col)
// exactly matching a sequential strict-< scan. Greedy "lowest row wins"
// claims via global atomicMin (claim[] pre-set to 0xFFFFFFFF).
// ---------------------------------------------------------------------------
__global__ __launch_bounds__(256) void rowmin_kernel(
    const float* __restrict__ costT, unsigned long long* __restrict__ upack,
    unsigned* __restrict__ claimg) {
  const int w = threadIdx.x >> 6, lane = threadIdx.x & 63;
  const int row = blockIdx.x * 4 + w;          // row = b*NN + t
  const float* rp = costT + (size_t)row * MM;
  unsigned long long best = ~0ull;
  #pragma unroll
  for (int s = 0; s < NSLOT; ++s) {
    const int j = s * 64 + lane;
    if (j < MM) {
      unsigned bts = __float_as_uint(rp[j]);
      bts = (bts & 0x80000000u) ? ~bts : (bts | 0x80000000u);
      const unsigned long long pk = ((unsigned long long)bts << 32) | (unsigned)j;
      if (pk < best) best = pk;
    }
  }
  #pragma unroll
  for (int m = 1; m < 64; m <<= 1) {
    const unsigned long long o = __shfl_xor(best, m);
    if (o < best) best = o;
  }
  if (lane == 0) {
    upack[row] = best;
    const int b = row >> 8;
    const int t = row & (NN - 1);
    const unsigned q = (unsigned)(best & 0xffffffffu);
    atomicMin(&claimg[b * MM + q], (unsigned)t);
  }
}

// ---------------------------------------------------------------------------
// Fallback cost kernel (used only if workspace is too small).
// ---------------------------------------------------------------------------
__global__ __launch_bounds__(256) void cost_kernel_fb(
    const float* __restrict__ logits, const float* __restrict__ boxes,
    const int* __restrict__ labels, const float* __restrict__ tbox,
    float* __restrict__ C, float* __restrict__ costT) {
#pragma clang fp contract(off)
  const int bq  = blockIdx.x;
  const int b   = bq / NQ;
  const int tid = threadIdx.x;
  __shared__ float lg[NCL];
  __shared__ float red[128];
  if (tid < NCL) lg[tid] = logits[(size_t)bq * NCL + tid];
  __syncthreads();
  if (tid < 128) red[tid] = (tid < NCL) ? lg[tid] : -INFINITY;
  __syncthreads();
  for (int s = 64; s > 0; s >>= 1) { if (tid < s) red[tid] = fmaxf(red[tid], red[tid+s]); __syncthreads(); }
  const float mx = red[0];
  __syncthreads();
  float e = 0.f;
  if (tid < NCL) e = expf(lg[tid] - mx);
  if (tid < 128) red[tid] = e;
  __syncthreads();
  for (int s = 64; s > 0; s >>= 1) { if (tid < s) red[tid] += red[tid+s]; __syncthreads(); }
  const float sm = red[0];
  __syncthreads();
  if (tid < NCL) lg[tid] = e / sm;
  __syncthreads();
  const float cx = boxes[(size_t)bq*4+0], cy = boxes[(size_t)bq*4+1];
  const float w  = boxes[(size_t)bq*4+2], h  = boxes[(size_t)bq*4+3];
  const float bx1 = cx - 0.5f*w, by1 = cy - 0.5f*h;
  const float bx2 = cx + 0.5f*w, by2 = cy + 0.5f*h;
  const float area1 = (bx2 - bx1) * (by2 - by1);
  const int q = bq - b * NQ;
  for (int jt = tid; jt < SUMT; jt += 256) {
    const float4 tb = ((const float4*)tbox)[jt];
    const int lab = labels[jt];
    const float cc = -lg[lab];
    const float d0 = fabsf(cx - tb.x), d1 = fabsf(cy - tb.y);
    const float d2 = fabsf(w - tb.z),  d3 = fabsf(h - tb.w);
    const float cb = ((d0 + d1) + d2) + d3;
    const float tx1 = tb.x - 0.5f*tb.z, ty1 = tb.y - 0.5f*tb.w;
    const float tx2 = tb.x + 0.5f*tb.z, ty2 = tb.y + 0.5f*tb.w;
    const float area2 = (tx2 - tx1) * (ty2 - ty1);
    const float ltx = fmaxf(bx1, tx1), lty = fmaxf(by1, ty1);
    const float rbx = fminf(bx2, tx2), rby = fminf(by2, ty2);
    const float iw = fmaxf(rbx - ltx, 0.f), ih = fmaxf(rby - lty, 0.f);
    const float inter = iw * ih;
    const float uni = (area1 + area2) - inter;
    const float iou = inter / uni;
    const float ex1 = fminf(bx1, tx1), ey1 = fminf(by1, ty1);
    const float ex2 = fmaxf(bx2, tx2), ey2 = fmaxf(by2, ty2);
    const float ew = fmaxf(ex2 - ex1, 0.f), eh = fmaxf(ey2 - ey1, 0.f);
    const float ea = ew * eh;
    const float giou = iou - (ea - uni) / ea;
    const float cval = (5.0f*cb + 1.0f*cc) + 2.0f*(-giou);
    C[(size_t)bq * SUMT + jt] = cval;
    if (costT && (jt >> 8) == b) costT[(size_t)jt * MM + q] = cval;
  }
}

// ---------------------------------------------------------------------------
// Kernel D: JV LSA (R1-proven ARR + Phase A offload).
// Phase A: duals u[i]=row-min + greedy claims (precomputed by rowmin_kernel
//   when upack!=null; else computed in-kernel by 256 threads).
// Phase A2 (wave 0): R1's augmenting row reduction: always steal the argmin
//   column (v[j1] -= mu2-mu1, u[i]=mu2), chain with the displaced row, global
//   cap 2048. Invariants (f64 dual feasibility + CS; v=0 on free columns
//   at init, only decreasing) hold after every step -> Phase B exact
//   regardless of where ARR stops. [Measured 369us total in R1.]
// Phase B (wave 0): Dijkstra for remaining unassigned rows, lazy deltas;
//   free columns all carry v<=0 from the same shared-decrement scheme, so
//   first-free-column termination is sound (rectangular LAP sink condition).
// ---------------------------------------------------------------------------
__global__ __launch_bounds__(256) void lsa_kernel(
    const float* __restrict__ C, const float* __restrict__ costT,
    const unsigned long long* __restrict__ upack,
    const unsigned* __restrict__ claimg,
    float* __restrict__ rows_out, float* __restrict__ cols_out) {
  const int b   = blockIdx.x;
  const int tid = threadIdx.x;

  __shared__ double u[NN + 1];
  __shared__ int    p[MM + 1];
  __shared__ int    wayl[MM + 1];
  __shared__ int    claim[MM + 1];
  __shared__ int    rowargmin[NN];
  __shared__ unsigned char rowass[NN];
  __shared__ int    listj[MM + 1];
  __shared__ double listD[MM + 1];

  // ---- Phase A: row minima + greedy claims ----
  for (int j = tid; j <= MM; j += 256) { p[j] = 0; claim[j] = INT_MAX; }
  if (upack) {
    const unsigned long long pk = upack[b * NN + tid];
    const unsigned key = (unsigned)(pk >> 32);
    const unsigned bts = (key & 0x80000000u) ? (key & 0x7fffffffu) : ~key;
    const int am = (int)(pk & 0xffffffffu);
    u[tid + 1] = (double)__uint_as_float(bts);
    const bool got = (claimg[b * MM + am] == (unsigned)tid);
    rowass[tid] = got ? 1 : 0;
    if (got) p[am + 1] = tid + 1;
    if (tid == 0) u[0] = 0.0;
    __syncthreads();
  } else {
    const float* rowptr = C + ((size_t)(b * NQ)) * SUMT + b * NT + tid;
    float mn = INFINITY; int am = 0;
    #pragma unroll 4
    for (int q = 0; q < NQ; ++q) {
      const float cv = rowptr[(size_t)q * SUMT];
      if (cv < mn) { mn = cv; am = q; }
    }
    u[tid + 1] = (double)mn;     // exact: pure f32 min, no arithmetic
    rowargmin[tid] = am;
    if (tid == 0) u[0] = 0.0;
    __syncthreads();
    atomicMin(&claim[rowargmin[tid] + 1], tid + 1);
    __syncthreads();
    {
      const int am2 = rowargmin[tid];
      const bool got = (claim[am2 + 1] == tid + 1);
      rowass[tid] = got ? 1 : 0;
      if (got) p[am2 + 1] = tid + 1;
    }
    __syncthreads();
  }
  if (tid >= 64) return;                   // phases A2/B are wave 0 only

  const int lane = tid;
  const float* slab = costT ? costT + (size_t)b * NT * MM : nullptr;
  double v_r[NSLOT];
  #pragma unroll
  for (int s = 0; s < NSLOT; ++s) v_r[s] = 0.0;

  // ---- Phase A2: R1 augmenting row reduction (wave 0, always-steal) ----
  if (slab) {
    int steps = 0;
    const int ARR_CAP = 2048;
    for (int i0 = 1; i0 <= NN && steps < ARR_CAP; ++i0) {
      if (rowass[i0 - 1]) continue;
      int i = i0;
      while (steps < ARR_CAP) {
        ++steps;
        const float* rowp = slab + (size_t)(i - 1) * MM;
        double b1 = INFINITY, b2 = INFINITY; int j1 = MM + 2;
        #pragma unroll
        for (int s = 0; s < NSLOT; ++s) {
          const int j = s * 64 + lane + 1;
          if (j <= MM) {
            const double cand = (double)rowp[j - 1] - v_r[s];
            if (cand < b1) { b2 = b1; b1 = cand; j1 = j; }
            else           { b2 = fmin(b2, cand); }
          }
        }
        #pragma unroll
        for (int m = 1; m < 64; m <<= 1) {
          const double ob1 = __shfl_xor(b1, m);
          const double ob2 = __shfl_xor(b2, m);
          const int    oj1 = __shfl_xor(j1, m);
          if (ob1 < b1 || (ob1 == b1 && oj1 < j1)) {
            b2 = fmin(b1, ob2); b1 = ob1; j1 = oj1;
          } else {
            b2 = fmin(b2, ob1);
          }
        }
        // all lanes agree: b1 = mu1 at column j1, b2 = mu2 (>= mu1)
        const double amt = ((b2 < INFINITY) ? b2 : b1) - b1;   // mu2 - mu1
        if (lane == ((j1 - 1) & 63)) v_r[(j1 - 1) >> 6] -= amt;
        const int k = p[j1];                 // read before overwrite
        if (lane == 0) {
          u[i] = b1 + amt;                   // u[i] = mu2 (equality at j1)
          p[j1] = i;
          rowass[i - 1] = 1;
          if (k != 0) rowass[k - 1] = 0;
        }
        if (k == 0) break;                   // chain ended at a free column
        i = k;
      }
    }
  }

  // ---- Phase B: Dijkstra for any remaining unassigned rows (wave 0) ----
  for (int ii = 1; ii <= NN; ++ii) {
    if (rowass[ii - 1]) continue;

    double M_r[NSLOT];
    #pragma unroll
    for (int s = 0; s < NSLOT; ++s) M_r[s] = INFINITY;
    unsigned int used = (lane < 4) ? 0u : (1u << 14);  // kill slot-14 tail
    int    lcount = 0;
    int    j0 = 0;
    double Dsel = 0.0;          // D at j0's selection (0 for virtual col)
    double D = 0.0;
    bool   okrow = true;

    while (true) {
      const int    i0 = (j0 == 0) ? ii : p[j0];
      const double us = u[i0] - Dsel;
      const float* rowp = slab ? slab + (size_t)(i0 - 1) * MM : nullptr;

      double best = INFINITY; int bestj = MM + 2;
      #pragma unroll
      for (int s = 0; s < NSLOT; ++s) {
        if (!(used & (1u << s))) {
          const int j = s * 64 + lane + 1;
          const float cf = rowp ? rowp[j - 1]
              : C[((size_t)(b*NQ + (j-1)))*SUMT + (b*NT + i0 - 1)];
          const double cand = ((double)cf - v_r[s]) - us;
          if (cand < M_r[s]) { M_r[s] = cand; wayl[j] = j0; }
          if (M_r[s] < best) { best = M_r[s]; bestj = j; }
        }
      }
      #pragma unroll
      for (int m = 1; m < 64; m <<= 1) {
        const double ov = __shfl_xor(best, m);
        const int    oj = __shfl_xor(bestj, m);
        if (ov < best || (ov == best && oj < bestj)) { best = ov; bestj = oj; }
      }
      const int j1 = bestj;
      if (j1 > MM) { okrow = false; break; }     // safety: no candidate (pathological)
      D = best;                                  // accumulated delta = M[j1]
      if (lane == ((j1 - 1) & 63)) used |= 1u << ((j1 - 1) >> 6);
      if (p[j1] == 0) { j0 = j1; break; }        // free column: done
      if (lane == 0) { listj[lcount] = j1; listD[lcount] = D; }
      lcount++;
      j0 = j1; Dsel = D;
    }

    if (okrow) {
      // batched dual updates (old p), then augmentation
      for (int e = 0; e < lcount; ++e) {
        const int    je = listj[e];
        const double amt = D - listD[e];
        if (lane == ((je - 1) & 63)) v_r[(je - 1) >> 6] -= amt;
        if (lane == 0) u[p[je]] += amt;
      }
      if (lane == 0) {
        u[ii] += D;                              // virtual column j0=0
        int jj = j0;
        while (jj) { const int jn = wayl[jj]; const int pn = (jn == 0) ? ii : p[jn]; p[jj] = pn; jj = jn; }
        rowass[ii - 1] = 1;
      }
    }
  }

  // ---- emit (query, target) pairs in ascending query order ----
  int base = 0;
  #pragma unroll
  for (int s = 0; s < NSLOT; ++s) {
    const int j = s * 64 + lane + 1;
    const bool a = (j <= MM) && (p[j] > 0);
    const unsigned long long mask = __ballot(a);
    const int rank = __popcll(mask & ((1ull << lane) - 1ull));
    if (a) {
      rows_out[b*NT + base + rank] = (float)(j - 1);
      cols_out[b*NT + base + rank] = (float)(p[j] - 1);
    }
    base += __popcll(mask);
  }
}

extern "C" void kernel_launch(void* const* d_in, const int* in_sizes, int n_in,
                              void* d_out, int out_size, void* d_ws, size_t ws_size,
                              hipStream_t stream) {
  const float* logits = (const float*)d_in[0];
  const float* boxes  = (const float*)d_in[1];
  const int*   labels = (const int*)d_in[2];
  const float* tbox   = (const float*)d_in[3];

  float* C    = (float*)d_out;
  float* rows = C + (size_t)BSZ * NQ * SUMT;
  float* cols = rows + (size_t)BSZ * NT;

  const size_t needT = (size_t)SUMT * MM * sizeof(float);        // ~14.7 MB
  const size_t needP = (size_t)BSZ * NQ * NCL * sizeof(float);   // ~5.3 MB
  const size_t needU = (size_t)BSZ * NN * sizeof(unsigned long long);
  const size_t needC = (size_t)BSZ * MM * sizeof(unsigned);

  if (ws_size >= needP + needT + needU + needC) {
    float* P     = (float*)d_ws;
    float* costT = P + (size_t)BSZ * NQ * NCL;
    unsigned long long* upack = (unsigned long long*)(costT + (size_t)SUMT * MM);
    unsigned* claimg = (unsigned*)(upack + (size_t)BSZ * NN);
    hipMemsetAsync(claimg, 0xFF, needC, stream);
    hipLaunchKernelGGL(prob_kernel, dim3(BSZ*NQ/4), dim3(256), 0, stream, logits, P);
    hipLaunchKernelGGL(cost_kernel2, dim3(SUMT/256, NQ/QCHUNK, BSZ), dim3(256), 0, stream,
                       P, boxes, labels, tbox, C);
    hipLaunchKernelGGL(transpose_kernel, dim3(15, 4, BSZ), dim3(256), 0, stream, C, costT);
    hipLaunchKernelGGL(rowmin_kernel, dim3(BSZ*NN/4), dim3(256), 0, stream, costT, upack, claimg);
    hipLaunchKernelGGL(lsa_kernel, dim3(BSZ), dim3(256), 0, stream,
                       C, costT, upack, claimg, rows, cols);
  } else if (ws_size >= needP + needT) {
    float* P     = (float*)d_ws;
    float* costT = P + (size_t)BSZ * NQ * NCL;
    hipLaunchKernelGGL(prob_kernel, dim3(BSZ*NQ/4), dim3(256), 0, stream, logits, P);
    hipLaunchKernelGGL(cost_kernel2, dim3(SUMT/256, NQ/QCHUNK, BSZ), dim3(256), 0, stream,
                       P, boxes, labels, tbox, C);
    hipLaunchKernelGGL(transpose_kernel, dim3(15, 4, BSZ), dim3(256), 0, stream, C, costT);
    hipLaunchKernelGGL(lsa_kernel, dim3(BSZ), dim3(256), 0, stream,
                       C, costT, (const unsigned long long*)nullptr,
                       (const unsigned*)nullptr, rows, cols);
  } else if (ws_size >= needT) {
    float* costT = (float*)d_ws;
    hipLaunchKernelGGL(cost_kernel_fb, dim3(BSZ*NQ), dim3(256), 0, stream,
                       logits, boxes, labels, tbox, C, costT);
    hipLaunchKernelGGL(lsa_kernel, dim3(BSZ), dim3(256), 0, stream,
                       C, costT, (const unsigned long long*)nullptr,
                       (const unsigned*)nullptr, rows, cols);
  } else {
    hipLaunchKernelGGL(cost_kernel_fb, dim3(BSZ*NQ), dim3(256), 0, stream,
                       logits, boxes, labels, tbox, C, (float*)nullptr);
    hipLaunchKernelGGL(lsa_kernel, dim3(BSZ), dim3(256), 0, stream,
                       C, (float*)nullptr, (const unsigned long long*)nullptr,
                       (const unsigned*)nullptr, rows, cols);
  }
}

// Round 7
// 407.651 us; speedup vs baseline: 2.5075x; 1.4794x over previous
//
#include <hip/hip_runtime.h>
#include <math.h>
#include <limits.h>

#define BSZ 16
#define NQ  900
#define NCL 92
#define NT  256
#define SUMT (BSZ*NT)   /* 4096 */
#define MM  NQ          /* JV columns (queries) */
#define NN  NT          /* JV rows (targets)    */
#define NSLOT 15        /* ceil(900/64) columns per lane */
#define QCHUNK 60       /* q's per cost block: 900 = 15*60 */
#define WAVES 8         /* bidding waves in lsa_kernel */
#define BLKT (WAVES*64) /* 512 threads */
#define RING 512        /* free-row ring buffer (in-flight <= 264) */
#define ARR_CAP 4000    /* global bid cap; Phase B finishes exactly */

// ---------------------------------------------------------------------------
// Kernel A: softmax probs, one wave per (b,q) row, shuffle-only.
// ---------------------------------------------------------------------------
__global__ __launch_bounds__(256) void prob_kernel(
    const float* __restrict__ logits, float* __restrict__ P) {
#pragma clang fp contract(off)
  const int w = threadIdx.x >> 6, lane = threadIdx.x & 63;
  const int r = blockIdx.x * 4 + w;
  const size_t base = (size_t)r * NCL;
  const float x1 = logits[base + lane];
  const float x2 = (lane + 64 < NCL) ? logits[base + lane + 64] : -INFINITY;
  float m = fmaxf(x1, x2);
  #pragma unroll
  for (int k = 1; k < 64; k <<= 1) m = fmaxf(m, __shfl_xor(m, k));
  const float e1 = expf(x1 - m);
  const float e2 = (lane + 64 < NCL) ? expf(x2 - m) : 0.f;
  float ssum = e1 + e2;
  #pragma unroll
  for (int k = 1; k < 64; k <<= 1) ssum += __shfl_xor(ssum, k);
  P[base + lane] = e1 / ssum;
  if (lane + 64 < NCL) P[base + lane + 64] = e2 / ssum;
}

// ---------------------------------------------------------------------------
// Kernel B: cost matrix, coalesced stores; per-block LDS staging of the
// 60 query boxes + 60x92 prob rows so the q-loop is LDS+VALU only.
// ---------------------------------------------------------------------------
__global__ __launch_bounds__(256) void cost_kernel2(
    const float* __restrict__ P, const float* __restrict__ boxes,
    const int* __restrict__ labels, const float* __restrict__ tbox,
    float* __restrict__ C) {
#pragma clang fp contract(off)
  const int tid = threadIdx.x;
  const int jt = blockIdx.x * 256 + tid;
  const int b  = blockIdx.z;
  const int q0 = blockIdx.y * QCHUNK;

  __shared__ float sP[QCHUNK * NCL];   // 5520 floats
  __shared__ float sB[QCHUNK * 4];     // 240 floats

  const size_t pbase = (size_t)(b * NQ + q0) * NCL;
  for (int x = tid; x < QCHUNK * NCL; x += 256) sP[x] = P[pbase + x];
  const size_t bbase = (size_t)(b * NQ + q0) * 4;
  if (tid < QCHUNK * 4) sB[tid] = boxes[bbase + tid];

  const float4 tb = ((const float4*)tbox)[jt];
  const int lab = labels[jt];
  const float tx1 = tb.x - 0.5f*tb.z, ty1 = tb.y - 0.5f*tb.w;
  const float tx2 = tb.x + 0.5f*tb.z, ty2 = tb.y + 0.5f*tb.w;
  const float area2 = (tx2 - tx1) * (ty2 - ty1);
  __syncthreads();

  for (int qq = 0; qq < QCHUNK; ++qq) {
    const float cx = sB[qq*4+0], cy = sB[qq*4+1];
    const float w  = sB[qq*4+2], h  = sB[qq*4+3];
    const float cc = -sP[qq*NCL + lab];
    const float bx1 = cx - 0.5f*w, by1 = cy - 0.5f*h;
    const float bx2 = cx + 0.5f*w, by2 = cy + 0.5f*h;
    const float area1 = (bx2 - bx1) * (by2 - by1);
    const float d0 = fabsf(cx - tb.x), d1 = fabsf(cy - tb.y);
    const float d2 = fabsf(w - tb.z),  d3 = fabsf(h - tb.w);
    const float cb = ((d0 + d1) + d2) + d3;
    const float ltx = fmaxf(bx1, tx1), lty = fmaxf(by1, ty1);
    const float rbx = fminf(bx2, tx2), rby = fminf(by2, ty2);
    const float iw = fmaxf(rbx - ltx, 0.f), ih = fmaxf(rby - lty, 0.f);
    const float inter = iw * ih;
    const float uni = (area1 + area2) - inter;
    const float iou = inter / uni;
    const float ex1 = fminf(bx1, tx1), ey1 = fminf(by1, ty1);
    const float ex2 = fmaxf(bx2, tx2), ey2 = fmaxf(by2, ty2);
    const float ew = fmaxf(ex2 - ex1, 0.f), eh = fmaxf(ey2 - ey1, 0.f);
    const float ea = ew * eh;
    const float giou = iou - (ea - uni) / ea;
    C[(size_t)(b*NQ + q0 + qq) * SUMT + jt] = (5.0f*cb + 1.0f*cc) + 2.0f*(-giou);
  }
}

// ---------------------------------------------------------------------------
// Kernel C: LDS-tiled transpose of the diagonal slabs: costT[b][t][q],
// fused with per-row minima: atomicMin of packed (ordered-f32-key<<32 | q)
// into upack[b*NN+t]. Packing/tie semantics identical to the old
// rowmin_kernel (lowest q wins ties via the u64 min; exact f32 key).
// upack must be pre-set to 0xFF...F.
// ---------------------------------------------------------------------------
__global__ __launch_bounds__(256) void transpose_kernel(
    const float* __restrict__ C, float* __restrict__ costT,
    unsigned long long* __restrict__ upack) {
  __shared__ float tile[64][65];
  const int b  = blockIdx.z;
  const int q0 = blockIdx.x * 64, t0 = blockIdx.y * 64;
  const int tx = threadIdx.x & 63, ty = threadIdx.x >> 6;
  #pragma unroll
  for (int i = 0; i < 16; ++i) {
    const int qq = ty + i*4;
    const int q = q0 + qq;
    if (q < NQ)
      tile[qq][tx] = C[((size_t)(b*NQ + q))*SUMT + b*NT + t0 + tx];
  }
  __syncthreads();
  #pragma unroll
  for (int i = 0; i < 16; ++i) {
    const int tt = ty + i*4;
    const int q = q0 + tx;
    if (q < NQ)
      costT[((size_t)(b*NT + t0 + tt))*MM + q] = tile[tx][tt];
  }
  if (upack && threadIdx.x < 64) {
    const int nq = (NQ - q0 < 64) ? (NQ - q0) : 64;
    unsigned long long best = ~0ull;
    for (int qq = 0; qq < nq; ++qq) {
      unsigned bts = __float_as_uint(tile[qq][threadIdx.x]);
      bts = (bts & 0x80000000u) ? ~bts : (bts | 0x80000000u);
      const unsigned long long pk =
          ((unsigned long long)bts << 32) | (unsigned)(q0 + qq);
      if (pk < best) best = pk;
    }
    atomicMin(&upack[b * NN + t0 + threadIdx.x], best);
  }
}

// ---------------------------------------------------------------------------
// Fallback cost kernel (used only if workspace is too small).
// ---------------------------------------------------------------------------
__global__ __launch_bounds__(256) void cost_kernel_fb(
    const float* __restrict__ logits, const float* __restrict__ boxes,
    const int* __restrict__ labels, const float* __restrict__ tbox,
    float* __restrict__ C, float* __restrict__ costT) {
#pragma clang fp contract(off)
  const int bq  = blockIdx.x;
  const int b   = bq / NQ;
  const int tid = threadIdx.x;
  __shared__ float lg[NCL];
  __shared__ float red[128];
  if (tid < NCL) lg[tid] = logits[(size_t)bq * NCL + tid];
  __syncthreads();
  if (tid < 128) red[tid] = (tid < NCL) ? lg[tid] : -INFINITY;
  __syncthreads();
  for (int s = 64; s > 0; s >>= 1) { if (tid < s) red[tid] = fmaxf(red[tid], red[tid+s]); __syncthreads(); }
  const float mx = red[0];
  __syncthreads();
  float e = 0.f;
  if (tid < NCL) e = expf(lg[tid] - mx);
  if (tid < 128) red[tid] = e;
  __syncthreads();
  for (int s = 64; s > 0; s >>= 1) { if (tid < s) red[tid] += red[tid+s]; __syncthreads(); }
  const float sm = red[0];
  __syncthreads();
  if (tid < NCL) lg[tid] = e / sm;
  __syncthreads();
  const float cx = boxes[(size_t)bq*4+0], cy = boxes[(size_t)bq*4+1];
  const float w  = boxes[(size_t)bq*4+2], h  = boxes[(size_t)bq*4+3];
  const float bx1 = cx - 0.5f*w, by1 = cy - 0.5f*h;
  const float bx2 = cx + 0.5f*w, by2 = cy + 0.5f*h;
  const float area1 = (bx2 - bx1) * (by2 - by1);
  const int q = bq - b * NQ;
  for (int jt = tid; jt < SUMT; jt += 256) {
    const float4 tb = ((const float4*)tbox)[jt];
    const int lab = labels[jt];
    const float cc = -lg[lab];
    const float d0 = fabsf(cx - tb.x), d1 = fabsf(cy - tb.y);
    const float d2 = fabsf(w - tb.z),  d3 = fabsf(h - tb.w);
    const float cb = ((d0 + d1) + d2) + d3;
    const float tx1 = tb.x - 0.5f*tb.z, ty1 = tb.y - 0.5f*tb.w;
    const float tx2 = tb.x + 0.5f*tb.z, ty2 = tb.y + 0.5f*tb.w;
    const float area2 = (tx2 - tx1) * (ty2 - ty1);
    const float ltx = fmaxf(bx1, tx1), lty = fmaxf(by1, ty1);
    const float rbx = fminf(bx2, tx2), rby = fminf(by2, ty2);
    const float iw = fmaxf(rbx - ltx, 0.f), ih = fmaxf(rby - lty, 0.f);
    const float inter = iw * ih;
    const float uni = (area1 + area2) - inter;
    const float iou = inter / uni;
    const float ex1 = fminf(bx1, tx1), ey1 = fminf(by1, ty1);
    const float ex2 = fmaxf(bx2, tx2), ey2 = fmaxf(by2, ty2);
    const float ew = fmaxf(ex2 - ex1, 0.f), eh = fmaxf(ey2 - ey1, 0.f);
    const float ea = ew * eh;
    const float giou = iou - (ea - uni) / ea;
    const float cval = (5.0f*cb + 1.0f*cc) + 2.0f*(-giou);
    C[(size_t)bq * SUMT + jt] = cval;
    if (costT && (jt >> 8) == b) costT[(size_t)jt * MM + q] = cval;
  }
}

// ---------------------------------------------------------------------------
// Kernel D: JV LSA, 512 threads/block, one block per image.
// Phase A: u[i]=row-min (decoded from upack, or in-kernel scan) + greedy
//   claims via LDS atomicMin (lowest row wins == sequential greedy).
// Phase A2: 8-way Jacobi augmenting-row-reduction. Each round, up to 8
//   waves scan distinct free rows vs round-start prices v; bids commit in
//   parallel to DISTINCT columns (same-column conflicts requeue). Soundness:
//   committed pair has reduced cost exactly 0 (CS); stale b2 <= true second
//   min, so u[i]=b2 keeps c-u-v >= 0 everywhere (feasibility); v only
//   decreases; columns never unassign, so free columns keep v=0 (rectangular
//   sink condition). Hard cap ARR_CAP; Phase B finishes exactly regardless.
// Phase B (wave 0): Dijkstra for remaining unassigned rows, lazy deltas.
// ---------------------------------------------------------------------------
__global__ __launch_bounds__(BLKT) void lsa_kernel(
    const float* __restrict__ C, const float* __restrict__ costT,
    const unsigned long long* __restrict__ upack,
    float* __restrict__ rows_out, float* __restrict__ cols_out) {
  const int b   = blockIdx.x;
  const int tid = threadIdx.x;

  __shared__ double u[NN + 1];
  __shared__ int    p[MM + 1];
  __shared__ int    wayl[MM + 1];
  __shared__ int    claim[MM + 1];
  __shared__ int    rowargmin[NN];
  __shared__ unsigned char rowass[NN];
  __shared__ int    listj[MM + 1];
  __shared__ double listD[MM + 1];
  __shared__ double vs[MM + 1];
  __shared__ int    qring[RING];
  __shared__ int    qhead_sh, qtail_sh, steps_sh;
  __shared__ int    bid_i[WAVES], bid_j[WAVES];
  __shared__ double bid_b1[WAVES], bid_b2[WAVES];

  // ---- Phase A: row minima + greedy claims (LDS) ----
  for (int j = tid; j <= MM; j += BLKT) { p[j] = 0; claim[j] = INT_MAX; vs[j] = 0.0; }
  if (upack) {
    if (tid < NN) {
      const unsigned long long pk = upack[b * NN + tid];
      const unsigned key = (unsigned)(pk >> 32);
      const unsigned bts = (key & 0x80000000u) ? (key & 0x7fffffffu) : ~key;
      u[tid + 1] = (double)__uint_as_float(bts);
      rowargmin[tid] = (int)(pk & 0xffffffffu);
    }
  } else if (costT || C) {
    if (tid < NN) {
      const float* rowptr = C + ((size_t)(b * NQ)) * SUMT + b * NT + tid;
      float mn = INFINITY; int am = 0;
      #pragma unroll 4
      for (int q = 0; q < NQ; ++q) {
        const float cv = rowptr[(size_t)q * SUMT];
        if (cv < mn) { mn = cv; am = q; }
      }
      u[tid + 1] = (double)mn;   // exact: pure f32 min, no arithmetic
      rowargmin[tid] = am;
    }
  }
  if (tid == 0) u[0] = 0.0;
  __syncthreads();
  if (tid < NN) atomicMin(&claim[rowargmin[tid] + 1], tid + 1);
  __syncthreads();
  if (tid < NN) {
    const int am = rowargmin[tid];
    const bool got = (claim[am + 1] == tid + 1);
    rowass[tid] = got ? 1 : 0;
    if (got) p[am + 1] = tid + 1;
  }
  __syncthreads();

  const int lane = tid & 63;
  const int wv   = tid >> 6;
  const float* slab = costT ? costT + (size_t)b * NT * MM : nullptr;

  // ---- build free-row queue (wave 0, ascending row index) ----
  if (tid < 64) {
    int fcnt = 0;
    #pragma unroll
    for (int c = 0; c < 4; ++c) {
      const bool fr = !rowass[c * 64 + tid];
      const unsigned long long mk = __ballot(fr);
      const int rk = __popcll(mk & ((1ull << tid) - 1ull));
      if (fr) qring[fcnt + rk] = c * 64 + tid + 1;
      fcnt += __popcll(mk);
    }
    if (tid == 0) { qhead_sh = 0; qtail_sh = fcnt; steps_sh = 0; }
  }
  __syncthreads();

  // ---- Phase A2: 8-way Jacobi ARR (all waves) ----
  if (slab) {
    while (true) {
      const int head = qhead_sh, tail = qtail_sh, st = steps_sh;
      if (head >= tail || st >= ARR_CAP) break;
      const int nact = ((tail - head) < WAVES) ? (tail - head) : WAVES;

      if (wv < nact) {
        const int i = qring[(head + wv) & (RING - 1)];
        const float* rowp = slab + (size_t)(i - 1) * MM;
        double b1 = INFINITY, b2 = INFINITY; int j1 = MM + 2;
        #pragma unroll
        for (int s = 0; s < NSLOT; ++s) {
          const int j = s * 64 + lane + 1;
          if (j <= MM) {
            const double cand = (double)rowp[j - 1] - vs[j];
            if (cand < b1) { b2 = b1; b1 = cand; j1 = j; }
            else           { b2 = fmin(b2, cand); }
          }
        }
        #pragma unroll
        for (int m = 1; m < 64; m <<= 1) {
          const double ob1 = __shfl_xor(b1, m);
          const double ob2 = __shfl_xor(b2, m);
          const int    oj1 = __shfl_xor(j1, m);
          if (ob1 < b1 || (ob1 == b1 && oj1 < j1)) {
            b2 = fmin(b1, ob2); b1 = ob1; j1 = oj1;
          } else {
            b2 = fmin(b2, ob1);
          }
        }
        if (lane == 0) { bid_i[wv] = i; bid_j[wv] = j1; bid_b1[wv] = b1; bid_b2[wv] = b2; }
      }
      __syncthreads();

      if (tid < nact) {            // parallel commit, one thread per bid
        const int j1 = bid_j[tid];
        bool dup = false;
        for (int e = 0; e < tid; ++e) if (bid_j[e] == j1) dup = true;
        if (dup) {
          const int slot = atomicAdd(&qtail_sh, 1);
          qring[slot & (RING - 1)] = bid_i[tid];       // requeue, rebid next round
        } else {
          const double amt = bid_b2[tid] - bid_b1[tid]; // >= 0
          vs[j1] -= amt;
          u[bid_i[tid]] = bid_b2[tid];
          const int k = p[j1];
          p[j1] = bid_i[tid];
          rowass[bid_i[tid] - 1] = 1;
          if (k) {
            rowass[k - 1] = 0;
            const int slot = atomicAdd(&qtail_sh, 1);
            qring[slot & (RING - 1)] = k;              // displaced row
          }
        }
      }
      if (tid == 0) { qhead_sh += nact; steps_sh += nact; }
      __syncthreads();
    }
  }

  if (tid >= 64) return;           // Phase B + emit: wave 0 only

  double v_r[NSLOT];
  #pragma unroll
  for (int s = 0; s < NSLOT; ++s) {
    const int j = s * 64 + lane + 1;
    v_r[s] = (j <= MM) ? vs[j] : 0.0;
  }

  // ---- Phase B: Dijkstra for any remaining unassigned rows (wave 0) ----
  for (int ii = 1; ii <= NN; ++ii) {
    if (rowass[ii - 1]) continue;

    double M_r[NSLOT];
    #pragma unroll
    for (int s = 0; s < NSLOT; ++s) M_r[s] = INFINITY;
    unsigned int used = (lane < 4) ? 0u : (1u << 14);  // kill slot-14 tail
    int    lcount = 0;
    int    j0 = 0;
    double Dsel = 0.0;          // D at j0's selection (0 for virtual col)
    double D = 0.0;
    bool   okrow = true;

    while (true) {
      const int    i0 = (j0 == 0) ? ii : p[j0];
      const double us = u[i0] - Dsel;
      const float* rowp = slab ? slab + (size_t)(i0 - 1) * MM : nullptr;

      double best = INFINITY; int bestj = MM + 2;
      #pragma unroll
      for (int s = 0; s < NSLOT; ++s) {
        if (!(used & (1u << s))) {
          const int j = s * 64 + lane + 1;
          const float cf = rowp ? rowp[j - 1]
              : C[((size_t)(b*NQ + (j-1)))*SUMT + (b*NT + i0 - 1)];
          const double cand = ((double)cf - v_r[s]) - us;
          if (cand < M_r[s]) { M_r[s] = cand; wayl[j] = j0; }
          if (M_r[s] < best) { best = M_r[s]; bestj = j; }
        }
      }
      #pragma unroll
      for (int m = 1; m < 64; m <<= 1) {
        const double ov = __shfl_xor(best, m);
        const int    oj = __shfl_xor(bestj, m);
        if (ov < best || (ov == best && oj < bestj)) { best = ov; bestj = oj; }
      }
      const int j1 = bestj;
      if (j1 > MM) { okrow = false; break; }     // safety: no candidate
      D = best;                                  // accumulated delta = M[j1]
      if (lane == ((j1 - 1) & 63)) used |= 1u << ((j1 - 1) >> 6);
      if (p[j1] == 0) { j0 = j1; break; }        // free column: done
      if (lane == 0) { listj[lcount] = j1; listD[lcount] = D; }
      lcount++;
      j0 = j1; Dsel = D;
    }

    if (okrow) {
      // batched dual updates (old p), then augmentation
      for (int e = 0; e < lcount; ++e) {
        const int    je = listj[e];
        const double amt = D - listD[e];
        if (lane == ((je - 1) & 63)) v_r[(je - 1) >> 6] -= amt;
        if (lane == 0) u[p[je]] += amt;
      }
      if (lane == 0) {
        u[ii] += D;                              // virtual column j0=0
        int jj = j0;
        while (jj) { const int jn = wayl[jj]; const int pn = (jn == 0) ? ii : p[jn]; p[jj] = pn; jj = jn; }
        rowass[ii - 1] = 1;
      }
    }
  }

  // ---- emit (query, target) pairs in ascending query order ----
  int base = 0;
  #pragma unroll
  for (int s = 0; s < NSLOT; ++s) {
    const int j = s * 64 + lane + 1;
    const bool a = (j <= MM) && (p[j] > 0);
    const unsigned long long mask = __ballot(a);
    const int rank = __popcll(mask & ((1ull << lane) - 1ull));
    if (a) {
      rows_out[b*NT + base + rank] = (float)(j - 1);
      cols_out[b*NT + base + rank] = (float)(p[j] - 1);
    }
    base += __popcll(mask);
  }
}

extern "C" void kernel_launch(void* const* d_in, const int* in_sizes, int n_in,
                              void* d_out, int out_size, void* d_ws, size_t ws_size,
                              hipStream_t stream) {
  const float* logits = (const float*)d_in[0];
  const float* boxes  = (const float*)d_in[1];
  const int*   labels = (const int*)d_in[2];
  const float* tbox   = (const float*)d_in[3];

  float* C    = (float*)d_out;
  float* rows = C + (size_t)BSZ * NQ * SUMT;
  float* cols = rows + (size_t)BSZ * NT;

  const size_t needT = (size_t)SUMT * MM * sizeof(float);        // ~14.7 MB
  const size_t needP = (size_t)BSZ * NQ * NCL * sizeof(float);   // ~5.3 MB
  const size_t needU = (size_t)BSZ * NN * sizeof(unsigned long long);

  if (ws_size >= needP + needT + needU) {
    float* P     = (float*)d_ws;
    float* costT = P + (size_t)BSZ * NQ * NCL;
    unsigned long long* upack = (unsigned long long*)(costT + (size_t)SUMT * MM);
    hipMemsetAsync(upack, 0xFF, needU, stream);
    hipLaunchKernelGGL(prob_kernel, dim3(BSZ*NQ/4), dim3(256), 0, stream, logits, P);
    hipLaunchKernelGGL(cost_kernel2, dim3(SUMT/256, NQ/QCHUNK, BSZ), dim3(256), 0, stream,
                       P, boxes, labels, tbox, C);
    hipLaunchKernelGGL(transpose_kernel, dim3(15, 4, BSZ), dim3(256), 0, stream,
                       C, costT, upack);
    hipLaunchKernelGGL(lsa_kernel, dim3(BSZ), dim3(BLKT), 0, stream,
                       C, costT, upack, rows, cols);
  } else if (ws_size >= needP + needT) {
    float* P     = (float*)d_ws;
    float* costT = P + (size_t)BSZ * NQ * NCL;
    hipLaunchKernelGGL(prob_kernel, dim3(BSZ*NQ/4), dim3(256), 0, stream, logits, P);
    hipLaunchKernelGGL(cost_kernel2, dim3(SUMT/256, NQ/QCHUNK, BSZ), dim3(256), 0, stream,
                       P, boxes, labels, tbox, C);
    hipLaunchKernelGGL(transpose_kernel, dim3(15, 4, BSZ), dim3(256), 0, stream,
                       C, costT, (unsigned long long*)nullptr);
    hipLaunchKernelGGL(lsa_kernel, dim3(BSZ), dim3(BLKT), 0, stream,
                       C, costT, (const unsigned long long*)nullptr, rows, cols);
  } else if (ws_size >= needT) {
    float* costT = (float*)d_ws;
    hipLaunchKernelGGL(cost_kernel_fb, dim3(BSZ*NQ), dim3(256), 0, stream,
                       logits, boxes, labels, tbox, C, costT);
    hipLaunchKernelGGL(lsa_kernel, dim3(BSZ), dim3(BLKT), 0, stream,
                       C, costT, (const unsigned long long*)nullptr, rows, cols);
  } else {
    hipLaunchKernelGGL(cost_kernel_fb, dim3(BSZ*NQ), dim3(256), 0, stream,
                       logits, boxes, labels, tbox, C, (float*)nullptr);
    hipLaunchKernelGGL(lsa_kernel, dim3(BSZ), dim3(BLKT), 0, stream,
                       C, (float*)nullptr, (const unsigned long long*)nullptr, rows, cols);
  }
}

// Round 8
// 388.736 us; speedup vs baseline: 2.6296x; 1.0487x over previous
//
#include <hip/hip_runtime.h>
#include <math.h>
#include <limits.h>

#define BSZ 16
#define NQ  900
#define NCL 92
#define NT  256
#define SUMT (BSZ*NT)   /* 4096 */
#define MM  NQ          /* JV columns (queries) */
#define NN  NT          /* JV rows (targets)    */
#define NSLOT 15        /* ceil(900/64) columns per lane */
#define QCHUNK 60       /* q's per cost block: 900 = 15*60 */
#define WAVES 16        /* bidding waves in lsa_kernel */
#define BLKT (WAVES*64) /* 1024 threads */
#define RING 512        /* free-row ring buffer (live <= ~264) */
#define ARR_CAP 4000    /* global bid cap; Phase B finishes exactly */

// ---------------------------------------------------------------------------
// Kernel A: softmax probs, one wave per (b,q) row, shuffle-only.
// ---------------------------------------------------------------------------
__global__ __launch_bounds__(256) void prob_kernel(
    const float* __restrict__ logits, float* __restrict__ P) {
#pragma clang fp contract(off)
  const int w = threadIdx.x >> 6, lane = threadIdx.x & 63;
  const int r = blockIdx.x * 4 + w;
  const size_t base = (size_t)r * NCL;
  const float x1 = logits[base + lane];
  const float x2 = (lane + 64 < NCL) ? logits[base + lane + 64] : -INFINITY;
  float m = fmaxf(x1, x2);
  #pragma unroll
  for (int k = 1; k < 64; k <<= 1) m = fmaxf(m, __shfl_xor(m, k));
  const float e1 = expf(x1 - m);
  const float e2 = (lane + 64 < NCL) ? expf(x2 - m) : 0.f;
  float ssum = e1 + e2;
  #pragma unroll
  for (int k = 1; k < 64; k <<= 1) ssum += __shfl_xor(ssum, k);
  P[base + lane] = e1 / ssum;
  if (lane + 64 < NCL) P[base + lane + 64] = e2 / ssum;
}

// ---------------------------------------------------------------------------
// Kernel B: cost matrix, coalesced C stores; per-block LDS staging of the
// 60 query boxes + 60x92 prob rows. FUSED: diag blocks (blockIdx.x == b)
// also write costT[b][t][q] (thread owns t=tid; its 60 q-values are a
// contiguous 240B run) and accumulate the packed row-min
// (ordered-f32-key<<32 | q) -> atomicMin into upack[b*NN+t]. Packing and
// u64-min tie semantics identical to the old rowmin (lowest q wins).
// upack must be pre-set to 0xFF...F.
// ---------------------------------------------------------------------------
__global__ __launch_bounds__(256) void cost_kernel2(
    const float* __restrict__ P, const float* __restrict__ boxes,
    const int* __restrict__ labels, const float* __restrict__ tbox,
    float* __restrict__ C, float* __restrict__ costT,
    unsigned long long* __restrict__ upack) {
#pragma clang fp contract(off)
  const int tid = threadIdx.x;
  const int jt = blockIdx.x * 256 + tid;
  const int b  = blockIdx.z;
  const int q0 = blockIdx.y * QCHUNK;
  const bool diag = (blockIdx.x == b) && (costT != nullptr);

  __shared__ float sP[QCHUNK * NCL];   // 5520 floats
  __shared__ float sB[QCHUNK * 4];     // 240 floats

  const size_t pbase = (size_t)(b * NQ + q0) * NCL;
  for (int x = tid; x < QCHUNK * NCL; x += 256) sP[x] = P[pbase + x];
  const size_t bbase = (size_t)(b * NQ + q0) * 4;
  if (tid < QCHUNK * 4) sB[tid] = boxes[bbase + tid];

  const float4 tb = ((const float4*)tbox)[jt];
  const int lab = labels[jt];
  const float tx1 = tb.x - 0.5f*tb.z, ty1 = tb.y - 0.5f*tb.w;
  const float tx2 = tb.x + 0.5f*tb.z, ty2 = tb.y + 0.5f*tb.w;
  const float area2 = (tx2 - tx1) * (ty2 - ty1);
  __syncthreads();

  float* tr = diag ? (costT + ((size_t)(b * NT + tid)) * MM + q0) : nullptr;
  unsigned long long best = ~0ull;

  for (int qq = 0; qq < QCHUNK; ++qq) {
    const float cx = sB[qq*4+0], cy = sB[qq*4+1];
    const float w  = sB[qq*4+2], h  = sB[qq*4+3];
    const float cc = -sP[qq*NCL + lab];
    const float bx1 = cx - 0.5f*w, by1 = cy - 0.5f*h;
    const float bx2 = cx + 0.5f*w, by2 = cy + 0.5f*h;
    const float area1 = (bx2 - bx1) * (by2 - by1);
    const float d0 = fabsf(cx - tb.x), d1 = fabsf(cy - tb.y);
    const float d2 = fabsf(w - tb.z),  d3 = fabsf(h - tb.w);
    const float cb = ((d0 + d1) + d2) + d3;
    const float ltx = fmaxf(bx1, tx1), lty = fmaxf(by1, ty1);
    const float rbx = fminf(bx2, tx2), rby = fminf(by2, ty2);
    const float iw = fmaxf(rbx - ltx, 0.f), ih = fmaxf(rby - lty, 0.f);
    const float inter = iw * ih;
    const float uni = (area1 + area2) - inter;
    const float iou = inter / uni;
    const float ex1 = fminf(bx1, tx1), ey1 = fminf(by1, ty1);
    const float ex2 = fmaxf(bx2, tx2), ey2 = fmaxf(by2, ty2);
    const float ew = fmaxf(ex2 - ex1, 0.f), eh = fmaxf(ey2 - ey1, 0.f);
    const float ea = ew * eh;
    const float giou = iou - (ea - uni) / ea;
    const float cval = (5.0f*cb + 1.0f*cc) + 2.0f*(-giou);
    C[(size_t)(b*NQ + q0 + qq) * SUMT + jt] = cval;
    if (diag) {
      tr[qq] = cval;
      unsigned bts = __float_as_uint(cval);
      bts = (bts & 0x80000000u) ? ~bts : (bts | 0x80000000u);
      const unsigned long long pk =
          ((unsigned long long)bts << 32) | (unsigned)(q0 + qq);
      if (pk < best) best = pk;
    }
  }
  if (diag && upack) atomicMin(&upack[b * NN + tid], best);
}

// ---------------------------------------------------------------------------
// Fallback cost kernel (used only if workspace is too small).
// ---------------------------------------------------------------------------
__global__ __launch_bounds__(256) void cost_kernel_fb(
    const float* __restrict__ logits, const float* __restrict__ boxes,
    const int* __restrict__ labels, const float* __restrict__ tbox,
    float* __restrict__ C, float* __restrict__ costT) {
#pragma clang fp contract(off)
  const int bq  = blockIdx.x;
  const int b   = bq / NQ;
  const int tid = threadIdx.x;
  __shared__ float lg[NCL];
  __shared__ float red[128];
  if (tid < NCL) lg[tid] = logits[(size_t)bq * NCL + tid];
  __syncthreads();
  if (tid < 128) red[tid] = (tid < NCL) ? lg[tid] : -INFINITY;
  __syncthreads();
  for (int s = 64; s > 0; s >>= 1) { if (tid < s) red[tid] = fmaxf(red[tid], red[tid+s]); __syncthreads(); }
  const float mx = red[0];
  __syncthreads();
  float e = 0.f;
  if (tid < NCL) e = expf(lg[tid] - mx);
  if (tid < 128) red[tid] = e;
  __syncthreads();
  for (int s = 64; s > 0; s >>= 1) { if (tid < s) red[tid] += red[tid+s]; __syncthreads(); }
  const float sm = red[0];
  __syncthreads();
  if (tid < NCL) lg[tid] = e / sm;
  __syncthreads();
  const float cx = boxes[(size_t)bq*4+0], cy = boxes[(size_t)bq*4+1];
  const float w  = boxes[(size_t)bq*4+2], h  = boxes[(size_t)bq*4+3];
  const float bx1 = cx - 0.5f*w, by1 = cy - 0.5f*h;
  const float bx2 = cx + 0.5f*w, by2 = cy + 0.5f*h;
  const float area1 = (bx2 - bx1) * (by2 - by1);
  const int q = bq - b * NQ;
  for (int jt = tid; jt < SUMT; jt += 256) {
    const float4 tb = ((const float4*)tbox)[jt];
    const int lab = labels[jt];
    const float cc = -lg[lab];
    const float d0 = fabsf(cx - tb.x), d1 = fabsf(cy - tb.y);
    const float d2 = fabsf(w - tb.z),  d3 = fabsf(h - tb.w);
    const float cb = ((d0 + d1) + d2) + d3;
    const float tx1 = tb.x - 0.5f*tb.z, ty1 = tb.y - 0.5f*tb.w;
    const float tx2 = tb.x + 0.5f*tb.z, ty2 = tb.y + 0.5f*tb.w;
    const float area2 = (tx2 - tx1) * (ty2 - ty1);
    const float ltx = fmaxf(bx1, tx1), lty = fmaxf(by1, ty1);
    const float rbx = fminf(bx2, tx2), rby = fminf(by2, ty2);
    const float iw = fmaxf(rbx - ltx, 0.f), ih = fmaxf(rby - lty, 0.f);
    const float inter = iw * ih;
    const float uni = (area1 + area2) - inter;
    const float iou = inter / uni;
    const float ex1 = fminf(bx1, tx1), ey1 = fminf(by1, ty1);
    const float ex2 = fmaxf(bx2, tx2), ey2 = fmaxf(by2, ty2);
    const float ew = fmaxf(ex2 - ex1, 0.f), eh = fmaxf(ey2 - ey1, 0.f);
    const float ea = ew * eh;
    const float giou = iou - (ea - uni) / ea;
    const float cval = (5.0f*cb + 1.0f*cc) + 2.0f*(-giou);
    C[(size_t)bq * SUMT + jt] = cval;
    if (costT && (jt >> 8) == b) costT[(size_t)jt * MM + q] = cval;
  }
}

// ---------------------------------------------------------------------------
// Kernel D: JV LSA, 1024 threads/block, one block per image.
// Phase A: u[i]=row-min (decoded from upack, or in-kernel scan) + greedy
//   claims via LDS atomicMin (lowest row wins == sequential greedy).
// Phase A2: 16-way Jacobi augmenting-row-reduction. Each round, up to 16
//   waves scan distinct free rows vs round-start prices v; bids commit in
//   parallel to DISTINCT columns (same-column conflicts requeue). Soundness:
//   committed pair has reduced cost exactly 0 (CS); stale b2 <= true second
//   min, so u[i]=b2 keeps c-u-v >= 0 everywhere (feasibility); v only
//   decreases; columns never unassign, so free columns keep v=0 (rectangular
//   sink condition). Hard cap ARR_CAP; Phase B finishes exactly regardless.
// Phase B (wave 0): Dijkstra for remaining unassigned rows, lazy deltas.
// ---------------------------------------------------------------------------
__global__ __launch_bounds__(BLKT) void lsa_kernel(
    const float* __restrict__ C, const float* __restrict__ costT,
    const unsigned long long* __restrict__ upack,
    float* __restrict__ rows_out, float* __restrict__ cols_out) {
  const int b   = blockIdx.x;
  const int tid = threadIdx.x;

  __shared__ double u[NN + 1];
  __shared__ int    p[MM + 1];
  __shared__ int    wayl[MM + 1];
  __shared__ int    claim[MM + 1];
  __shared__ int    rowargmin[NN];
  __shared__ unsigned char rowass[NN];
  __shared__ int    listj[MM + 1];
  __shared__ double listD[MM + 1];
  __shared__ double vs[MM + 1];
  __shared__ int    qring[RING];
  __shared__ int    qhead_sh, qtail_sh, steps_sh;
  __shared__ int    bid_i[WAVES], bid_j[WAVES];
  __shared__ double bid_b1[WAVES], bid_b2[WAVES];

  // ---- Phase A: row minima + greedy claims (LDS) ----
  for (int j = tid; j <= MM; j += BLKT) { p[j] = 0; claim[j] = INT_MAX; vs[j] = 0.0; }
  if (upack) {
    if (tid < NN) {
      const unsigned long long pk = upack[b * NN + tid];
      const unsigned key = (unsigned)(pk >> 32);
      const unsigned bts = (key & 0x80000000u) ? (key & 0x7fffffffu) : ~key;
      u[tid + 1] = (double)__uint_as_float(bts);
      rowargmin[tid] = (int)(pk & 0xffffffffu);
    }
  } else if (costT || C) {
    if (tid < NN) {
      const float* rowptr = C + ((size_t)(b * NQ)) * SUMT + b * NT + tid;
      float mn = INFINITY; int am = 0;
      #pragma unroll 4
      for (int q = 0; q < NQ; ++q) {
        const float cv = rowptr[(size_t)q * SUMT];
        if (cv < mn) { mn = cv; am = q; }
      }
      u[tid + 1] = (double)mn;   // exact: pure f32 min, no arithmetic
      rowargmin[tid] = am;
    }
  }
  if (tid == 0) u[0] = 0.0;
  __syncthreads();
  if (tid < NN) atomicMin(&claim[rowargmin[tid] + 1], tid + 1);
  __syncthreads();
  if (tid < NN) {
    const int am = rowargmin[tid];
    const bool got = (claim[am + 1] == tid + 1);
    rowass[tid] = got ? 1 : 0;
    if (got) p[am + 1] = tid + 1;
  }
  __syncthreads();

  const int lane = tid & 63;
  const int wv   = tid >> 6;
  const float* slab = costT ? costT + (size_t)b * NT * MM : nullptr;

  // ---- build free-row queue (wave 0, ascending row index) ----
  if (tid < 64) {
    int fcnt = 0;
    #pragma unroll
    for (int c = 0; c < 4; ++c) {
      const bool fr = !rowass[c * 64 + tid];
      const unsigned long long mk = __ballot(fr);
      const int rk = __popcll(mk & ((1ull << tid) - 1ull));
      if (fr) qring[fcnt + rk] = c * 64 + tid + 1;
      fcnt += __popcll(mk);
    }
    if (tid == 0) { qhead_sh = 0; qtail_sh = fcnt; steps_sh = 0; }
  }
  __syncthreads();

  // ---- Phase A2: 16-way Jacobi ARR (all waves) ----
  if (slab) {
    while (true) {
      const int head = qhead_sh, tail = qtail_sh, st = steps_sh;
      if (head >= tail || st >= ARR_CAP) break;
      const int nact = ((tail - head) < WAVES) ? (tail - head) : WAVES;

      if (wv < nact) {
        const int i = qring[(head + wv) & (RING - 1)];
        const float* rowp = slab + (size_t)(i - 1) * MM;
        double b1 = INFINITY, b2 = INFINITY; int j1 = MM + 2;
        #pragma unroll
        for (int s = 0; s < NSLOT; ++s) {
          const int j = s * 64 + lane + 1;
          if (j <= MM) {
            const double cand = (double)rowp[j - 1] - vs[j];
            if (cand < b1) { b2 = b1; b1 = cand; j1 = j; }
            else           { b2 = fmin(b2, cand); }
          }
        }
        #pragma unroll
        for (int m = 1; m < 64; m <<= 1) {
          const double ob1 = __shfl_xor(b1, m);
          const double ob2 = __shfl_xor(b2, m);
          const int    oj1 = __shfl_xor(j1, m);
          if (ob1 < b1 || (ob1 == b1 && oj1 < j1)) {
            b2 = fmin(b1, ob2); b1 = ob1; j1 = oj1;
          } else {
            b2 = fmin(b2, ob1);
          }
        }
        if (lane == 0) { bid_i[wv] = i; bid_j[wv] = j1; bid_b1[wv] = b1; bid_b2[wv] = b2; }
      }
      __syncthreads();

      if (tid < nact) {            // parallel commit, one thread per bid
        const int j1 = bid_j[tid];
        bool dup = false;
        for (int e = 0; e < tid; ++e) if (bid_j[e] == j1) dup = true;
        if (dup) {
          const int slot = atomicAdd(&qtail_sh, 1);
          qring[slot & (RING - 1)] = bid_i[tid];       // requeue, rebid next round
        } else {
          const double amt = bid_b2[tid] - bid_b1[tid]; // >= 0
          vs[j1] -= amt;
          u[bid_i[tid]] = bid_b2[tid];
          const int k = p[j1];
          p[j1] = bid_i[tid];
          rowass[bid_i[tid] - 1] = 1;
          if (k) {
            rowass[k - 1] = 0;
            const int slot = atomicAdd(&qtail_sh, 1);
            qring[slot & (RING - 1)] = k;              // displaced row
          }
        }
      }
      if (tid == 0) { qhead_sh += nact; steps_sh += nact; }
      __syncthreads();
    }
  }

  if (tid >= 64) return;           // Phase B + emit: wave 0 only

  double v_r[NSLOT];
  #pragma unroll
  for (int s = 0; s < NSLOT; ++s) {
    const int j = s * 64 + lane + 1;
    v_r[s] = (j <= MM) ? vs[j] : 0.0;
  }

  // ---- Phase B: Dijkstra for any remaining unassigned rows (wave 0) ----
  for (int ii = 1; ii <= NN; ++ii) {
    if (rowass[ii - 1]) continue;

    double M_r[NSLOT];
    #pragma unroll
    for (int s = 0; s < NSLOT; ++s) M_r[s] = INFINITY;
    unsigned int used = (lane < 4) ? 0u : (1u << 14);  // kill slot-14 tail
    int    lcount = 0;
    int    j0 = 0;
    double Dsel = 0.0;          // D at j0's selection (0 for virtual col)
    double D = 0.0;
    bool   okrow = true;

    while (true) {
      const int    i0 = (j0 == 0) ? ii : p[j0];
      const double us = u[i0] - Dsel;
      const float* rowp = slab ? slab + (size_t)(i0 - 1) * MM : nullptr;

      double best = INFINITY; int bestj = MM + 2;
      #pragma unroll
      for (int s = 0; s < NSLOT; ++s) {
        if (!(used & (1u << s))) {
          const int j = s * 64 + lane + 1;
          const float cf = rowp ? rowp[j - 1]
              : C[((size_t)(b*NQ + (j-1)))*SUMT + (b*NT + i0 - 1)];
          const double cand = ((double)cf - v_r[s]) - us;
          if (cand < M_r[s]) { M_r[s] = cand; wayl[j] = j0; }
          if (M_r[s] < best) { best = M_r[s]; bestj = j; }
        }
      }
      #pragma unroll
      for (int m = 1; m < 64; m <<= 1) {
        const double ov = __shfl_xor(best, m);
        const int    oj = __shfl_xor(bestj, m);
        if (ov < best || (ov == best && oj < bestj)) { best = ov; bestj = oj; }
      }
      const int j1 = bestj;
      if (j1 > MM) { okrow = false; break; }     // safety: no candidate
      D = best;                                  // accumulated delta = M[j1]
      if (lane == ((j1 - 1) & 63)) used |= 1u << ((j1 - 1) >> 6);
      if (p[j1] == 0) { j0 = j1; break; }        // free column: done
      if (lane == 0) { listj[lcount] = j1; listD[lcount] = D; }
      lcount++;
      j0 = j1; Dsel = D;
    }

    if (okrow) {
      // batched dual updates (old p), then augmentation
      for (int e = 0; e < lcount; ++e) {
        const int    je = listj[e];
        const double amt = D - listD[e];
        if (lane == ((je - 1) & 63)) v_r[(je - 1) >> 6] -= amt;
        if (lane == 0) u[p[je]] += amt;
      }
      if (lane == 0) {
        u[ii] += D;                              // virtual column j0=0
        int jj = j0;
        while (jj) { const int jn = wayl[jj]; const int pn = (jn == 0) ? ii : p[jn]; p[jj] = pn; jj = jn; }
        rowass[ii - 1] = 1;
      }
    }
  }

  // ---- emit (query, target) pairs in ascending query order ----
  int base = 0;
  #pragma unroll
  for (int s = 0; s < NSLOT; ++s) {
    const int j = s * 64 + lane + 1;
    const bool a = (j <= MM) && (p[j] > 0);
    const unsigned long long mask = __ballot(a);
    const int rank = __popcll(mask & ((1ull << lane) - 1ull));
    if (a) {
      rows_out[b*NT + base + rank] = (float)(j - 1);
      cols_out[b*NT + base + rank] = (float)(p[j] - 1);
    }
    base += __popcll(mask);
  }
}

extern "C" void kernel_launch(void* const* d_in, const int* in_sizes, int n_in,
                              void* d_out, int out_size, void* d_ws, size_t ws_size,
                              hipStream_t stream) {
  const float* logits = (const float*)d_in[0];
  const float* boxes  = (const float*)d_in[1];
  const int*   labels = (const int*)d_in[2];
  const float* tbox   = (const float*)d_in[3];

  float* C    = (float*)d_out;
  float* rows = C + (size_t)BSZ * NQ * SUMT;
  float* cols = rows + (size_t)BSZ * NT;

  const size_t needT = (size_t)SUMT * MM * sizeof(float);        // ~14.7 MB
  const size_t needP = (size_t)BSZ * NQ * NCL * sizeof(float);   // ~5.3 MB
  const size_t needU = (size_t)BSZ * NN * sizeof(unsigned long long);

  if (ws_size >= needP + needT + needU) {
    float* P     = (float*)d_ws;
    float* costT = P + (size_t)BSZ * NQ * NCL;
    unsigned long long* upack = (unsigned long long*)(costT + (size_t)SUMT * MM);
    hipMemsetAsync(upack, 0xFF, needU, stream);
    hipLaunchKernelGGL(prob_kernel, dim3(BSZ*NQ/4), dim3(256), 0, stream, logits, P);
    hipLaunchKernelGGL(cost_kernel2, dim3(SUMT/256, NQ/QCHUNK, BSZ), dim3(256), 0, stream,
                       P, boxes, labels, tbox, C, costT, upack);
    hipLaunchKernelGGL(lsa_kernel, dim3(BSZ), dim3(BLKT), 0, stream,
                       C, costT, upack, rows, cols);
  } else if (ws_size >= needP + needT) {
    float* P     = (float*)d_ws;
    float* costT = P + (size_t)BSZ * NQ * NCL;
    hipLaunchKernelGGL(prob_kernel, dim3(BSZ*NQ/4), dim3(256), 0, stream, logits, P);
    hipLaunchKernelGGL(cost_kernel2, dim3(SUMT/256, NQ/QCHUNK, BSZ), dim3(256), 0, stream,
                       P, boxes, labels, tbox, C, costT, (unsigned long long*)nullptr);
    hipLaunchKernelGGL(lsa_kernel, dim3(BSZ), dim3(BLKT), 0, stream,
                       C, costT, (const unsigned long long*)nullptr, rows, cols);
  } else if (ws_size >= needT) {
    float* costT = (float*)d_ws;
    hipLaunchKernelGGL(cost_kernel_fb, dim3(BSZ*NQ), dim3(256), 0, stream,
                       logits, boxes, labels, tbox, C, costT);
    hipLaunchKernelGGL(lsa_kernel, dim3(BSZ), dim3(BLKT), 0, stream,
                       C, costT, (const unsigned long long*)nullptr, rows, cols);
  } else {
    hipLaunchKernelGGL(cost_kernel_fb, dim3(BSZ*NQ), dim3(256), 0, stream,
                       logits, boxes, labels, tbox, C, (float*)nullptr);
    hipLaunchKernelGGL(lsa_kernel, dim3(BSZ), dim3(BLKT), 0, stream,
                       C, (float*)nullptr, (const unsigned long long*)nullptr, rows, cols);
  }
}